// Round 1
// baseline (11322.386 us; speedup 1.0000x reference)
//
#include <hip/hip_runtime.h>
#include <hip/hip_bf16.h>
#include <cstddef>

// Dims (fixed by the problem)
#define BB 8
#define SS 1024
#define DD 512
#define HH 8
#define HD 64
#define LL 6
#define FFD 1024
#define IND 24
#define EPS 1e-5f

// ---------------------------------------------------------------------------
// Input projection + positional-encoding gather: h[t][d] = x[t]@W + b + pe[pos[t]]
// ---------------------------------------------------------------------------
__global__ __launch_bounds__(512) void inproj_kernel(
    const float* __restrict__ x, const int* __restrict__ pos,
    const float* __restrict__ pe, const float* __restrict__ W,
    const float* __restrict__ b, float* __restrict__ h) {
  int t = blockIdx.x;      // token 0..8191
  int d = threadIdx.x;     // 0..511
  __shared__ float xs[IND];
  if (d < IND) xs[d] = x[(size_t)t * IND + d];
  __syncthreads();
  int p = pos[t];
  float acc = b[d] + pe[(size_t)p * DD + d];
#pragma unroll
  for (int k = 0; k < IND; ++k) acc += xs[k] * W[k * DD + d];
  h[(size_t)t * DD + d] = acc;
}

// ---------------------------------------------------------------------------
// Generic tiled fp32 GEMM: C[M][N] = A[M][K] @ W[K][N] + bias (+optional ReLU)
// 64x64 block tile, 256 threads, 4x4 micro-tile, BK=16.
// ---------------------------------------------------------------------------
__global__ __launch_bounds__(256) void gemm_kernel(
    const float* __restrict__ A, const float* __restrict__ W,
    const float* __restrict__ bias, float* __restrict__ C,
    int M, int N, int K, int relu) {
  __shared__ float As[16][65];   // As[k][m], stride 65 -> 2-way conflicts (free)
  __shared__ float Ws[16][68];   // Ws[k][n], stride 68 -> aligned float4
  int tid = threadIdx.x;
  int n0 = blockIdx.x * 64;
  int m0 = blockIdx.y * 64;
  int arow = tid >> 2, akq = tid & 3;   // A-tile load mapping (row, k-quad)
  int wk = tid >> 4, wn = tid & 15;     // W-tile load mapping (k, n-quad)
  int ty = tid >> 4, tx = tid & 15;     // compute mapping
  float acc[4][4] = {};
  const float* Aptr = A + (size_t)(m0 + arow) * K + akq * 4;
  const float* Wptr = W + (size_t)wk * N + n0 + wn * 4;
  for (int k0 = 0; k0 < K; k0 += 16) {
    float4 a4 = *(const float4*)(Aptr + k0);
    float4 w4 = *(const float4*)(Wptr + (size_t)k0 * N);
    As[akq * 4 + 0][arow] = a4.x;
    As[akq * 4 + 1][arow] = a4.y;
    As[akq * 4 + 2][arow] = a4.z;
    As[akq * 4 + 3][arow] = a4.w;
    *(float4*)&Ws[wk][wn * 4] = w4;
    __syncthreads();
#pragma unroll
    for (int kk = 0; kk < 16; ++kk) {
      float a0 = As[kk][ty * 4 + 0];
      float a1 = As[kk][ty * 4 + 1];
      float a2 = As[kk][ty * 4 + 2];
      float a3 = As[kk][ty * 4 + 3];
      float4 wv = *(const float4*)&Ws[kk][tx * 4];
      acc[0][0] += a0 * wv.x; acc[0][1] += a0 * wv.y; acc[0][2] += a0 * wv.z; acc[0][3] += a0 * wv.w;
      acc[1][0] += a1 * wv.x; acc[1][1] += a1 * wv.y; acc[1][2] += a1 * wv.z; acc[1][3] += a1 * wv.w;
      acc[2][0] += a2 * wv.x; acc[2][1] += a2 * wv.y; acc[2][2] += a2 * wv.z; acc[2][3] += a2 * wv.w;
      acc[3][0] += a3 * wv.x; acc[3][1] += a3 * wv.y; acc[3][2] += a3 * wv.z; acc[3][3] += a3 * wv.w;
    }
    __syncthreads();
  }
  float4 bv = *(const float4*)&bias[n0 + tx * 4];
#pragma unroll
  for (int i = 0; i < 4; ++i) {
    int m = m0 + ty * 4 + i;
    float4 o;
    o.x = acc[i][0] + bv.x;
    o.y = acc[i][1] + bv.y;
    o.z = acc[i][2] + bv.z;
    o.w = acc[i][3] + bv.w;
    if (relu) {
      o.x = fmaxf(o.x, 0.f); o.y = fmaxf(o.y, 0.f);
      o.z = fmaxf(o.z, 0.f); o.w = fmaxf(o.w, 0.f);
    }
    *(float4*)&C[(size_t)m * N + n0 + tx * 4] = o;
  }
}

// ---------------------------------------------------------------------------
// Attention: one block per (b, h, 4-query chunk). 4 waves, one query each.
// qkv layout per token: [H][3*HD] = [h][ q(0:64) k(64:128) v(128:192) ]
// vals output layout: [token][h*HD + d]
// ---------------------------------------------------------------------------
__global__ __launch_bounds__(256) void attn_kernel(
    const float* __restrict__ qkv, float* __restrict__ vals) {
  __shared__ float Kst[64 * 65];  // K/V chunk staging, row-major stride 65
  __shared__ float qs[4][64];
  __shared__ float lg[4][1024];   // per-wave logits -> unnormalized probs
  int bid = blockIdx.x;
  int qc = bid & 255;          // query chunk (4 queries each)
  int h = (bid >> 8) & 7;
  int b = bid >> 11;
  int tid = threadIdx.x;
  int wid = tid >> 6, lane = tid & 63;
  const size_t tok0 = (size_t)b * SS;
  const int q = qc * 4 + wid;  // this wave's query index

  // stage q for this wave
  qs[wid][lane] = qkv[(tok0 + q) * 1536 + h * 192 + lane];

  const float* kbase = qkv + tok0 * 1536 + h * 192 + 64;
  const float* vbase = qkv + tok0 * 1536 + h * 192 + 128;

  float lmax = -1e30f;
  for (int c = 0; c < 16; ++c) {
    // stage K chunk (keys c*64 .. c*64+63), 4096 floats by 256 threads
#pragma unroll
    for (int r = 0; r < 4; ++r) {
      int idx = r * 256 + tid;
      int j = idx >> 4, dq = idx & 15;
      float4 v4 = *(const float4*)(kbase + (size_t)(c * 64 + j) * 1536 + dq * 4);
      float* dst = &Kst[j * 65 + dq * 4];
      dst[0] = v4.x; dst[1] = v4.y; dst[2] = v4.z; dst[3] = v4.w;
    }
    __syncthreads();
    // lane computes dot(q, K[c*64+lane])
    float s = 0.f;
    const float* kr = &Kst[lane * 65];
    const float4* qv = (const float4*)qs[wid];
#pragma unroll
    for (int d4 = 0; d4 < 16; ++d4) {
      float4 q4 = qv[d4];
      s += q4.x * kr[d4 * 4 + 0] + q4.y * kr[d4 * 4 + 1] +
           q4.z * kr[d4 * 4 + 2] + q4.w * kr[d4 * 4 + 3];
    }
    s *= 0.125f;  // 1/sqrt(64)
    lg[wid][c * 64 + lane] = s;
    lmax = fmaxf(lmax, s);
    __syncthreads();
  }
  // softmax (unnormalized; divide at the end)
#pragma unroll
  for (int off = 32; off; off >>= 1) lmax = fmaxf(lmax, __shfl_xor(lmax, off));
  float ssum = 0.f;
#pragma unroll
  for (int c = 0; c < 16; ++c) {
    float p = __expf(lg[wid][c * 64 + lane] - lmax);
    lg[wid][c * 64 + lane] = p;
    ssum += p;
  }
#pragma unroll
  for (int off = 32; off; off >>= 1) ssum += __shfl_xor(ssum, off);
  float inv = 1.f / ssum;

  // PV: lane owns output dim d = lane
  float acc = 0.f;
  for (int c = 0; c < 16; ++c) {
#pragma unroll
    for (int r = 0; r < 4; ++r) {
      int idx = r * 256 + tid;
      int j = idx >> 4, dq = idx & 15;
      float4 v4 = *(const float4*)(vbase + (size_t)(c * 64 + j) * 1536 + dq * 4);
      float* dst = &Kst[j * 65 + dq * 4];
      dst[0] = v4.x; dst[1] = v4.y; dst[2] = v4.z; dst[3] = v4.w;
    }
    __syncthreads();
    const float4* pv = (const float4*)&lg[wid][c * 64];
#pragma unroll
    for (int j4 = 0; j4 < 16; ++j4) {
      float4 p4 = pv[j4];
      acc += p4.x * Kst[(j4 * 4 + 0) * 65 + lane];
      acc += p4.y * Kst[(j4 * 4 + 1) * 65 + lane];
      acc += p4.z * Kst[(j4 * 4 + 2) * 65 + lane];
      acc += p4.w * Kst[(j4 * 4 + 3) * 65 + lane];
    }
    __syncthreads();
  }
  vals[(tok0 + q) * DD + h * HD + lane] = acc * inv;
}

// ---------------------------------------------------------------------------
// Fused residual + LayerNorm: h = LN(h + res) * g + b   (row-wise, D=512)
// ---------------------------------------------------------------------------
__global__ __launch_bounds__(64) void ln_residual_kernel(
    float* __restrict__ h, const float* __restrict__ res,
    const float* __restrict__ g, const float* __restrict__ bb) {
  int row = blockIdx.x;
  int lane = threadIdx.x;
  size_t base = (size_t)row * DD + lane * 8;
  float4 v0 = *(const float4*)&h[base];
  float4 v1 = *(const float4*)&h[base + 4];
  float4 r0 = *(const float4*)&res[base];
  float4 r1 = *(const float4*)&res[base + 4];
  float xv[8];
  xv[0] = v0.x + r0.x; xv[1] = v0.y + r0.y; xv[2] = v0.z + r0.z; xv[3] = v0.w + r0.w;
  xv[4] = v1.x + r1.x; xv[5] = v1.y + r1.y; xv[6] = v1.z + r1.z; xv[7] = v1.w + r1.w;
  float s = 0.f, sq = 0.f;
#pragma unroll
  for (int i = 0; i < 8; ++i) { s += xv[i]; sq += xv[i] * xv[i]; }
#pragma unroll
  for (int off = 32; off; off >>= 1) {
    s += __shfl_xor(s, off);
    sq += __shfl_xor(sq, off);
  }
  float mu = s * (1.f / DD);
  float var = sq * (1.f / DD) - mu * mu;
  float rs = rsqrtf(var + EPS);
  float4 g0 = *(const float4*)&g[lane * 8];
  float4 g1 = *(const float4*)&g[lane * 8 + 4];
  float4 b0 = *(const float4*)&bb[lane * 8];
  float4 b1 = *(const float4*)&bb[lane * 8 + 4];
  float4 o0, o1;
  o0.x = (xv[0] - mu) * rs * g0.x + b0.x;
  o0.y = (xv[1] - mu) * rs * g0.y + b0.y;
  o0.z = (xv[2] - mu) * rs * g0.z + b0.z;
  o0.w = (xv[3] - mu) * rs * g0.w + b0.w;
  o1.x = (xv[4] - mu) * rs * g1.x + b1.x;
  o1.y = (xv[5] - mu) * rs * g1.y + b1.y;
  o1.z = (xv[6] - mu) * rs * g1.z + b1.z;
  o1.w = (xv[7] - mu) * rs * g1.w + b1.w;
  *(float4*)&h[base] = o0;
  *(float4*)&h[base + 4] = o1;
}

// ---------------------------------------------------------------------------
// Mean pool over sequence: pooled[b][d] = mean_s h[b][s][d]
// ---------------------------------------------------------------------------
__global__ __launch_bounds__(512) void pool_kernel(
    const float* __restrict__ h, float* __restrict__ pooled) {
  int b = blockIdx.x, d = threadIdx.x;
  float s = 0.f;
  for (int t = 0; t < SS; ++t) s += h[((size_t)b * SS + t) * DD + d];
  pooled[b * DD + d] = s * (1.f / SS);
}

// ---------------------------------------------------------------------------
// Head: y = pooled @ W1 + b1 ; z = relu(LN(y)) ; out = z @ W2 + b2
// One block per batch row, 512 threads.
// ---------------------------------------------------------------------------
__global__ __launch_bounds__(512) void head_kernel(
    const float* __restrict__ pooled, const float* __restrict__ W1,
    const float* __restrict__ b1, const float* __restrict__ g,
    const float* __restrict__ bb, const float* __restrict__ W2,
    const float* __restrict__ b2, float* __restrict__ out) {
  int b = blockIdx.x, tid = threadIdx.x;
  int wid = tid >> 6, lane = tid & 63;
  __shared__ float ps[DD];
  __shared__ float red_s[8];
  __shared__ float red_q[8];
  ps[tid] = pooled[b * DD + tid];
  __syncthreads();
  float acc = b1[tid];
  for (int k = 0; k < DD; ++k) acc += ps[k] * W1[(size_t)k * DD + tid];
  // block LayerNorm over the 512 accs
  float s = acc, sq = acc * acc;
#pragma unroll
  for (int off = 32; off; off >>= 1) {
    s += __shfl_xor(s, off);
    sq += __shfl_xor(sq, off);
  }
  if (lane == 0) { red_s[wid] = s; red_q[wid] = sq; }
  __syncthreads();
  float S = 0.f, Q = 0.f;
#pragma unroll
  for (int i = 0; i < 8; ++i) { S += red_s[i]; Q += red_q[i]; }
  float mu = S * (1.f / DD);
  float var = Q * (1.f / DD) - mu * mu;
  float rs = rsqrtf(var + EPS);
  float z = (acc - mu) * rs * g[tid] + bb[tid];
  float r = fmaxf(z, 0.f);
  float v = r * W2[tid];
#pragma unroll
  for (int off = 32; off; off >>= 1) v += __shfl_xor(v, off);
  __syncthreads();
  if (lane == 0) red_s[wid] = v;
  __syncthreads();
  if (tid == 0) {
    float t = 0.f;
#pragma unroll
    for (int i = 0; i < 8; ++i) t += red_s[i];
    out[b] = t + b2[0];
  }
}

// ---------------------------------------------------------------------------
extern "C" void kernel_launch(void* const* d_in, const int* in_sizes, int n_in,
                              void* d_out, int out_size, void* d_ws, size_t ws_size,
                              hipStream_t stream) {
  const float* x    = (const float*)d_in[0];
  const int*   pos  = (const int*)d_in[1];
  const float* pe   = (const float*)d_in[2];
  const float* inW  = (const float*)d_in[3];
  const float* inb  = (const float*)d_in[4];
  const float* qkvW = (const float*)d_in[5];
  const float* qkvb = (const float*)d_in[6];
  const float* oW   = (const float*)d_in[7];
  const float* ob   = (const float*)d_in[8];
  const float* f1W  = (const float*)d_in[9];
  const float* f1b  = (const float*)d_in[10];
  const float* f2W  = (const float*)d_in[11];
  const float* f2b  = (const float*)d_in[12];
  const float* l1g  = (const float*)d_in[13];
  const float* l1b  = (const float*)d_in[14];
  const float* l2g  = (const float*)d_in[15];
  const float* l2b  = (const float*)d_in[16];
  const float* o1W  = (const float*)d_in[17];
  const float* o1b  = (const float*)d_in[18];
  const float* og   = (const float*)d_in[19];
  const float* obb  = (const float*)d_in[20];
  const float* o2W  = (const float*)d_in[21];
  const float* o2b  = (const float*)d_in[22];
  float* out = (float*)d_out;
  float* ws = (float*)d_ws;

  const size_t NTOK = (size_t)BB * SS;           // 8192
  float* h    = ws;                              // 8192*512
  float* big  = ws + NTOK * DD;                  // 8192*1536 (qkv)
  float* proj = big;                             // 8192*512 (reuses qkv lo)
  float* ff1  = big + NTOK * DD;                 // 8192*1024 (reuses qkv hi)
  float* vals = big + NTOK * 1536;               // 8192*512
  float* pooled = vals + NTOK * DD;              // 8*512

  inproj_kernel<<<NTOK, DD, 0, stream>>>(x, pos, pe, inW, inb, h);

  for (int l = 0; l < LL; ++l) {
    // QKV projection: [8192,512] @ [512,1536]
    gemm_kernel<<<dim3(1536 / 64, NTOK / 64), 256, 0, stream>>>(
        h, qkvW + (size_t)l * DD * 1536, qkvb + (size_t)l * 1536, big,
        NTOK, 1536, DD, 0);
    // attention
    attn_kernel<<<BB * HH * (SS / 4), 256, 0, stream>>>(big, vals);
    // output projection: [8192,512] @ [512,512]
    gemm_kernel<<<dim3(DD / 64, NTOK / 64), 256, 0, stream>>>(
        vals, oW + (size_t)l * DD * DD, ob + (size_t)l * DD, proj,
        NTOK, DD, DD, 0);
    // h = LN(h + attn_out)
    ln_residual_kernel<<<NTOK, 64, 0, stream>>>(h, proj, l1g + l * DD, l1b + l * DD);
    // FF1 + ReLU: [8192,512] @ [512,1024]
    gemm_kernel<<<dim3(FFD / 64, NTOK / 64), 256, 0, stream>>>(
        h, f1W + (size_t)l * DD * FFD, f1b + (size_t)l * FFD, ff1,
        NTOK, FFD, DD, 1);
    // FF2: [8192,1024] @ [1024,512]
    gemm_kernel<<<dim3(DD / 64, NTOK / 64), 256, 0, stream>>>(
        ff1, f2W + (size_t)l * FFD * DD, f2b + (size_t)l * DD, proj,
        NTOK, DD, FFD, 0);
    // h = LN(h + ff)
    ln_residual_kernel<<<NTOK, 64, 0, stream>>>(h, proj, l2g + l * DD, l2b + l * DD);
  }

  pool_kernel<<<BB, DD, 0, stream>>>(h, pooled);
  head_kernel<<<BB, DD, 0, stream>>>(pooled, o1W, o1b, og, obb, o2W, o2b, out);
}

// Round 2
// 1333.660 us; speedup vs baseline: 8.4897x; 8.4897x over previous
//
#include <hip/hip_runtime.h>
#include <cstddef>

#define BB 8
#define SS 1024
#define DDIM 512
#define EPS 1e-5f

typedef short bf16x8 __attribute__((ext_vector_type(8)));
typedef float f32x4 __attribute__((ext_vector_type(4)));
typedef unsigned short u16x8 __attribute__((ext_vector_type(8)));

__device__ __forceinline__ unsigned short f2bf(float x) {
  unsigned u = __float_as_uint(x);
  return (unsigned short)((u + 0x7FFFu + ((u >> 16) & 1u)) >> 16);
}

// ---------------------------------------------------------------------------
// Input projection + PE gather -> h (fp32) and hb (bf16)
// ---------------------------------------------------------------------------
__global__ __launch_bounds__(512) void inproj_kernel(
    const float* __restrict__ x, const int* __restrict__ pos,
    const float* __restrict__ pe, const float* __restrict__ Wp,
    const float* __restrict__ bp, float* __restrict__ h,
    unsigned short* __restrict__ hb) {
  int t = blockIdx.x, d = threadIdx.x;
  __shared__ float xs[24];
  if (d < 24) xs[d] = x[(size_t)t * 24 + d];
  __syncthreads();
  float acc = bp[d] + pe[(size_t)pos[t] * 512 + d];
#pragma unroll
  for (int k = 0; k < 24; ++k) acc += xs[k] * Wp[k * 512 + d];
  h[(size_t)t * 512 + d] = acc;
  hb[(size_t)t * 512 + d] = f2bf(acc);
}

// ---------------------------------------------------------------------------
// Per-layer weight cast+transpose: W[K][N] fp32 -> Wt[N][K] bf16 (4 segments)
// ---------------------------------------------------------------------------
__global__ __launch_bounds__(256) void wcast_kernel(
    const float* __restrict__ qw, const float* __restrict__ ow,
    const float* __restrict__ f1w, const float* __restrict__ f2w,
    unsigned short* __restrict__ qd, unsigned short* __restrict__ od,
    unsigned short* __restrict__ f1d, unsigned short* __restrict__ f2d) {
  __shared__ float sm[64][65];
  int bid = blockIdx.x;
  const float* src; unsigned short* dst; int K, N, tile;
  if (bid < 192)      { src = qw;  dst = qd;  K = 512;  N = 1536; tile = bid; }
  else if (bid < 256) { src = ow;  dst = od;  K = 512;  N = 512;  tile = bid - 192; }
  else if (bid < 384) { src = f1w; dst = f1d; K = 512;  N = 1024; tile = bid - 256; }
  else                { src = f2w; dst = f2d; K = 1024; N = 512;  tile = bid - 384; }
  int nt = N >> 6;
  int tk = tile / nt, tn = tile % nt;
  int k0 = tk * 64, n0 = tn * 64;
  int tid = threadIdx.x;
#pragma unroll
  for (int it = 0; it < 16; ++it) {
    int idx = it * 256 + tid;
    int ki = idx >> 6, ni = idx & 63;
    sm[ki][ni] = src[(size_t)(k0 + ki) * N + n0 + ni];
  }
  __syncthreads();
#pragma unroll
  for (int it = 0; it < 16; ++it) {
    int idx = it * 256 + tid;
    int ni = idx >> 6, ki = idx & 63;
    dst[(size_t)(n0 + ni) * K + k0 + ki] = f2bf(sm[ki][ni]);
  }
}

// ---------------------------------------------------------------------------
// bf16 MFMA GEMM: C[M][N] = A[M][K] @ W[K][N] (+bias). W given transposed as
// Wt[N][K]. 128x128 tile, BK=32, 4 waves (2x2), 4x4 16x16x32 frags per wave.
// MODE 0: fp32 out. MODE 1: bf16 out + ReLU. MODE 2: qkv head-major scatter.
// ---------------------------------------------------------------------------
template <int MODE>
__global__ __launch_bounds__(256) void gemm_bf16(
    const unsigned short* __restrict__ A, const unsigned short* __restrict__ Bw,
    const float* __restrict__ bias, float* __restrict__ Cf,
    unsigned short* __restrict__ Cb, unsigned short* __restrict__ q_out,
    unsigned short* __restrict__ k_out, unsigned short* __restrict__ v_out,
    int M, int N, int K) {
  __shared__ unsigned short As[128 * 32];
  __shared__ unsigned short Bs[128 * 32];
  int tid = threadIdx.x;
  int w = tid >> 6, l = tid & 63;
  int wm = w >> 1, wn = w & 1;
  int cl = l & 15, kg = l >> 4;
  int n0 = blockIdx.x * 128, m0 = blockIdx.y * 128;
  f32x4 acc[4][4];
#pragma unroll
  for (int i = 0; i < 4; ++i)
#pragma unroll
    for (int j = 0; j < 4; ++j) acc[i][j] = f32x4{0.f, 0.f, 0.f, 0.f};

  const unsigned short* Ap = A + (size_t)m0 * K;
  const unsigned short* Bp = Bw + (size_t)n0 * K;

  for (int k0 = 0; k0 < K; k0 += 32) {
    __syncthreads();
#pragma unroll
    for (int c = 0; c < 2; ++c) {
      int idx = c * 256 + tid;
      int r = idx >> 2, kq = idx & 3;
      uint4 av = *(const uint4*)(Ap + (size_t)r * K + k0 + kq * 8);
      *(uint4*)&As[r * 32 + kq * 8] = av;
      uint4 bv = *(const uint4*)(Bp + (size_t)r * K + k0 + kq * 8);
      *(uint4*)&Bs[r * 32 + kq * 8] = bv;
    }
    __syncthreads();
    bf16x8 af[4], bfr[4];
#pragma unroll
    for (int i = 0; i < 4; ++i) {
      af[i]  = *(const bf16x8*)&As[(wm * 64 + i * 16 + cl) * 32 + kg * 8];
      bfr[i] = *(const bf16x8*)&Bs[(wn * 64 + i * 16 + cl) * 32 + kg * 8];
    }
#pragma unroll
    for (int i = 0; i < 4; ++i)
#pragma unroll
      for (int j = 0; j < 4; ++j)
        acc[i][j] = __builtin_amdgcn_mfma_f32_16x16x32_bf16(af[i], bfr[j], acc[i][j], 0, 0, 0);
  }

  int rl = kg * 4;
#pragma unroll
  for (int i = 0; i < 4; ++i) {
    int mbase = m0 + wm * 64 + i * 16 + rl;
#pragma unroll
    for (int j = 0; j < 4; ++j) {
      int col = n0 + wn * 64 + j * 16 + cl;
      float bv = bias[col];
      if (MODE == 0) {
#pragma unroll
        for (int r = 0; r < 4; ++r)
          Cf[(size_t)(mbase + r) * N + col] = acc[i][j][r] + bv;
      } else if (MODE == 1) {
#pragma unroll
        for (int r = 0; r < 4; ++r)
          Cb[(size_t)(mbase + r) * N + col] = f2bf(fmaxf(acc[i][j][r] + bv, 0.f));
      } else {
        int hh = col / 192;
        int rem = col - hh * 192;
        int which = rem >> 6, d = rem & 63;
        unsigned short* dst = (which == 0) ? q_out : ((which == 1) ? k_out : v_out);
#pragma unroll
        for (int r = 0; r < 4; ++r) {
          int m = mbase + r;
          int b = m >> 10, s = m & 1023;
          dst[(((size_t)(b * 8 + hh)) * 1024 + s) * 64 + d] = f2bf(acc[i][j][r] + bv);
        }
      }
    }
  }
}

// ---------------------------------------------------------------------------
// Flash attention, bf16 MFMA. Block = (b*8+h, 64-query tile), 4 waves x 16 q.
// qT/kT/vT: [B*H][S][64] bf16. Out: valsb[tok][512] bf16 (col = h*64+d).
// ---------------------------------------------------------------------------
__global__ __launch_bounds__(256) void attn_mfma(
    const unsigned short* __restrict__ qT, const unsigned short* __restrict__ kT,
    const unsigned short* __restrict__ vT, unsigned short* __restrict__ valsb) {
  __shared__ unsigned short Ks[64 * 64];   // [k][d], byte ^ ((k&7)<<4)
  __shared__ unsigned short Vs[64 * 64];   // [d][k], byte ^ (((d&7)^(d>>3))<<4)
  __shared__ unsigned short Ps[4][1024];   // per-wave [q16][k64], byte ^ ((q&7)<<4)

  int bh = blockIdx.x >> 4;
  int qt = blockIdx.x & 15;
  int b = bh >> 3, h = bh & 7;
  int tid = threadIdx.x;
  int w = tid >> 6, l = tid & 63;
  int cl = l & 15, kg = l >> 4;
  int rl = kg * 4;

  const unsigned short* qbase = qT + (((size_t)bh * 1024) + qt * 64 + w * 16) * 64;
  bf16x8 aq[2];
  aq[0] = *(const bf16x8*)(qbase + cl * 64 + kg * 8);
  aq[1] = *(const bf16x8*)(qbase + cl * 64 + 32 + kg * 8);

  float m_r[4], l_r[4];
  f32x4 accO[4];
#pragma unroll
  for (int r = 0; r < 4; ++r) { m_r[r] = -1e30f; l_r[r] = 0.f; }
#pragma unroll
  for (int df = 0; df < 4; ++df) accO[df] = f32x4{0.f, 0.f, 0.f, 0.f};

  const unsigned short* kgb = kT + (size_t)bh * 1024 * 64;
  const unsigned short* vgb = vT + (size_t)bh * 1024 * 64;
  char* Pw = (char*)&Ps[w][0];

  for (int c = 0; c < 16; ++c) {
    __syncthreads();
    // stage K chunk (swizzled row-major)
#pragma unroll
    for (int it = 0; it < 2; ++it) {
      int idx = it * 256 + tid;
      int kk = idx >> 3, a = idx & 7;
      uint4 v = *(const uint4*)(kgb + ((size_t)(c * 64 + kk)) * 64 + a * 8);
      int byteoff = (kk * 128 + a * 16) ^ ((kk & 7) << 4);
      *(uint4*)((char*)Ks + byteoff) = v;
    }
    // stage V chunk transposed (swizzled)
#pragma unroll
    for (int it = 0; it < 2; ++it) {
      int idx = it * 256 + tid;
      int kk = idx >> 3, a = idx & 7;
      uint4 v = *(const uint4*)(vgb + ((size_t)(c * 64 + kk)) * 64 + a * 8);
      const unsigned short* vp = (const unsigned short*)&v;
#pragma unroll
      for (int i = 0; i < 8; ++i) {
        int d = a * 8 + i;
        int byteoff = (d * 128 + kk * 2) ^ (((d & 7) ^ a) << 4);
        *(unsigned short*)((char*)Vs + byteoff) = vp[i];
      }
    }
    __syncthreads();

    // QK^T: S[16q][64k] per wave
    f32x4 s[4];
#pragma unroll
    for (int kf = 0; kf < 4; ++kf) {
      s[kf] = f32x4{0.f, 0.f, 0.f, 0.f};
#pragma unroll
      for (int ks = 0; ks < 2; ++ks) {
        int row = kf * 16 + cl;
        int byteoff = (row * 128 + ks * 64 + kg * 16) ^ ((row & 7) << 4);
        bf16x8 bk = *(const bf16x8*)((char*)Ks + byteoff);
        s[kf] = __builtin_amdgcn_mfma_f32_16x16x32_bf16(aq[ks], bk, s[kf], 0, 0, 0);
      }
    }

    // online softmax: rows live in 16-lane groups (same kg), cols = cl + kf*16
    float cm[4];
#pragma unroll
    for (int r = 0; r < 4; ++r)
      cm[r] = fmaxf(fmaxf(s[0][r], s[1][r]), fmaxf(s[2][r], s[3][r]));
#pragma unroll
    for (int off = 1; off < 16; off <<= 1)
#pragma unroll
      for (int r = 0; r < 4; ++r) cm[r] = fmaxf(cm[r], __shfl_xor(cm[r], off));

    float alpha[4];
#pragma unroll
    for (int r = 0; r < 4; ++r) {
      float mn = fmaxf(m_r[r], cm[r] * 0.125f);
      alpha[r] = __expf(m_r[r] - mn);
      m_r[r] = mn;
    }

    float rs[4] = {0.f, 0.f, 0.f, 0.f};
#pragma unroll
    for (int kf = 0; kf < 4; ++kf)
#pragma unroll
      for (int r = 0; r < 4; ++r) {
        float p = __expf(s[kf][r] * 0.125f - m_r[r]);
        rs[r] += p;
        int row = rl + r;
        int byteoff = (row * 128 + (kf * 16 + cl) * 2) ^ ((row & 7) << 4);
        *(unsigned short*)(Pw + byteoff) = f2bf(p);
      }
#pragma unroll
    for (int off = 1; off < 16; off <<= 1)
#pragma unroll
      for (int r = 0; r < 4; ++r) rs[r] += __shfl_xor(rs[r], off);
#pragma unroll
    for (int r = 0; r < 4; ++r) l_r[r] = l_r[r] * alpha[r] + rs[r];
#pragma unroll
    for (int df = 0; df < 4; ++df)
#pragma unroll
      for (int r = 0; r < 4; ++r) accO[df][r] *= alpha[r];

    // PV: O[16q][64d] += P @ V
#pragma unroll
    for (int ks = 0; ks < 2; ++ks) {
      int prow = cl;
      int pboff = (prow * 128 + ks * 64 + kg * 16) ^ ((prow & 7) << 4);
      bf16x8 ap = *(const bf16x8*)(Pw + pboff);
#pragma unroll
      for (int df = 0; df < 4; ++df) {
        int d = df * 16 + cl;
        int key = (d & 7) ^ ((d >> 3) & 7);
        int vboff = (d * 128 + ks * 64 + kg * 16) ^ (key << 4);
        bf16x8 bv = *(const bf16x8*)((char*)Vs + vboff);
        accO[df] = __builtin_amdgcn_mfma_f32_16x16x32_bf16(ap, bv, accO[df], 0, 0, 0);
      }
    }
  }

  // epilogue
  float inv[4];
#pragma unroll
  for (int r = 0; r < 4; ++r) inv[r] = 1.f / l_r[r];
#pragma unroll
  for (int df = 0; df < 4; ++df)
#pragma unroll
    for (int r = 0; r < 4; ++r) {
      int q = qt * 64 + w * 16 + rl + r;
      int d = df * 16 + cl;
      valsb[(((size_t)b * 1024) + q) * 512 + h * 64 + d] = f2bf(accO[df][r] * inv[r]);
    }
}

// ---------------------------------------------------------------------------
// Fused residual + LayerNorm -> h (fp32) + hb (bf16). 4 rows/block (1/wave).
// ---------------------------------------------------------------------------
__global__ __launch_bounds__(256) void ln_residual(
    float* __restrict__ h, const float* __restrict__ res,
    const float* __restrict__ g, const float* __restrict__ bb,
    unsigned short* __restrict__ hb) {
  int row = blockIdx.x * 4 + (threadIdx.x >> 6);
  int lane = threadIdx.x & 63;
  size_t base = (size_t)row * 512 + lane * 8;
  float4 v0 = *(const float4*)&h[base];
  float4 v1 = *(const float4*)&h[base + 4];
  float4 r0 = *(const float4*)&res[base];
  float4 r1 = *(const float4*)&res[base + 4];
  float xv[8];
  xv[0] = v0.x + r0.x; xv[1] = v0.y + r0.y; xv[2] = v0.z + r0.z; xv[3] = v0.w + r0.w;
  xv[4] = v1.x + r1.x; xv[5] = v1.y + r1.y; xv[6] = v1.z + r1.z; xv[7] = v1.w + r1.w;
  float s = 0.f, sq = 0.f;
#pragma unroll
  for (int i = 0; i < 8; ++i) { s += xv[i]; sq += xv[i] * xv[i]; }
#pragma unroll
  for (int off = 32; off; off >>= 1) { s += __shfl_xor(s, off); sq += __shfl_xor(sq, off); }
  float mu = s * (1.f / 512.f);
  float var = sq * (1.f / 512.f) - mu * mu;
  float rstd = rsqrtf(var + EPS);
  float4 g0 = *(const float4*)&g[lane * 8];
  float4 g1 = *(const float4*)&g[lane * 8 + 4];
  float4 b0 = *(const float4*)&bb[lane * 8];
  float4 b1 = *(const float4*)&bb[lane * 8 + 4];
  float o[8];
  o[0] = (xv[0] - mu) * rstd * g0.x + b0.x;
  o[1] = (xv[1] - mu) * rstd * g0.y + b0.y;
  o[2] = (xv[2] - mu) * rstd * g0.z + b0.z;
  o[3] = (xv[3] - mu) * rstd * g0.w + b0.w;
  o[4] = (xv[4] - mu) * rstd * g1.x + b1.x;
  o[5] = (xv[5] - mu) * rstd * g1.y + b1.y;
  o[6] = (xv[6] - mu) * rstd * g1.z + b1.z;
  o[7] = (xv[7] - mu) * rstd * g1.w + b1.w;
  *(float4*)&h[base] = make_float4(o[0], o[1], o[2], o[3]);
  *(float4*)&h[base + 4] = make_float4(o[4], o[5], o[6], o[7]);
  u16x8 hv;
#pragma unroll
  for (int i = 0; i < 8; ++i) hv[i] = f2bf(o[i]);
  *(u16x8*)&hb[base] = hv;
}

// ---------------------------------------------------------------------------
// Mean-pool partials: partial[(b*8+c)][d] = sum over 128 tokens
// ---------------------------------------------------------------------------
__global__ __launch_bounds__(512) void pool_kernel(
    const float* __restrict__ h, float* __restrict__ partial) {
  int b = blockIdx.x >> 3, c = blockIdx.x & 7, d = threadIdx.x;
  float s = 0.f;
  for (int t = 0; t < 128; ++t)
    s += h[((size_t)b * 1024 + c * 128 + t) * 512 + d];
  partial[(size_t)blockIdx.x * 512 + d] = s;
}

// ---------------------------------------------------------------------------
// Head: pooled@W1+b1 -> LN -> ReLU -> @W2+b2. One block per batch row.
// ---------------------------------------------------------------------------
__global__ __launch_bounds__(512) void head_kernel(
    const float* __restrict__ partial, const float* __restrict__ W1,
    const float* __restrict__ b1, const float* __restrict__ g,
    const float* __restrict__ bb, const float* __restrict__ W2,
    const float* __restrict__ b2, float* __restrict__ out) {
  int b = blockIdx.x, tid = threadIdx.x;
  int wid = tid >> 6, lane = tid & 63;
  __shared__ float ps[512];
  __shared__ float red_s[8];
  __shared__ float red_q[8];
  float pv = 0.f;
#pragma unroll
  for (int c = 0; c < 8; ++c) pv += partial[((size_t)(b * 8 + c)) * 512 + tid];
  ps[tid] = pv * (1.f / 1024.f);
  __syncthreads();
  float acc = b1[tid];
  for (int k = 0; k < 512; ++k) acc += ps[k] * W1[(size_t)k * 512 + tid];
  float s = acc, sq = acc * acc;
#pragma unroll
  for (int off = 32; off; off >>= 1) { s += __shfl_xor(s, off); sq += __shfl_xor(sq, off); }
  if (lane == 0) { red_s[wid] = s; red_q[wid] = sq; }
  __syncthreads();
  float S = 0.f, Q = 0.f;
#pragma unroll
  for (int i = 0; i < 8; ++i) { S += red_s[i]; Q += red_q[i]; }
  float mu = S * (1.f / 512.f);
  float var = Q * (1.f / 512.f) - mu * mu;
  float rstd = rsqrtf(var + EPS);
  float z = (acc - mu) * rstd * g[tid] + bb[tid];
  float r = fmaxf(z, 0.f);
  float v = r * W2[tid];
#pragma unroll
  for (int off = 32; off; off >>= 1) v += __shfl_xor(v, off);
  __syncthreads();
  if (lane == 0) red_s[wid] = v;
  __syncthreads();
  if (tid == 0) {
    float t = 0.f;
#pragma unroll
    for (int i = 0; i < 8; ++i) t += red_s[i];
    out[b] = t + b2[0];
  }
}

// ---------------------------------------------------------------------------
extern "C" void kernel_launch(void* const* d_in, const int* in_sizes, int n_in,
                              void* d_out, int out_size, void* d_ws, size_t ws_size,
                              hipStream_t stream) {
  const float* x    = (const float*)d_in[0];
  const int*   pos  = (const int*)d_in[1];
  const float* pe   = (const float*)d_in[2];
  const float* inW  = (const float*)d_in[3];
  const float* inb  = (const float*)d_in[4];
  const float* qkvW = (const float*)d_in[5];
  const float* qkvb = (const float*)d_in[6];
  const float* oW   = (const float*)d_in[7];
  const float* ob   = (const float*)d_in[8];
  const float* f1W  = (const float*)d_in[9];
  const float* f1b  = (const float*)d_in[10];
  const float* f2W  = (const float*)d_in[11];
  const float* f2b  = (const float*)d_in[12];
  const float* l1g  = (const float*)d_in[13];
  const float* l1b  = (const float*)d_in[14];
  const float* l2g  = (const float*)d_in[15];
  const float* l2b  = (const float*)d_in[16];
  const float* o1W  = (const float*)d_in[17];
  const float* o1b  = (const float*)d_in[18];
  const float* og   = (const float*)d_in[19];
  const float* obb  = (const float*)d_in[20];
  const float* o2W  = (const float*)d_in[21];
  const float* o2b  = (const float*)d_in[22];
  float* out = (float*)d_out;

  char* W = (char*)d_ws;
  float*          h     = (float*)(W + 0);                 // 16 MB fp32
  unsigned short* hb    = (unsigned short*)(W + 16777216); // 8 MB bf16
  unsigned short* qTb   = (unsigned short*)(W + 25165824); // 8 MB
  unsigned short* kTb   = (unsigned short*)(W + 33554432); // 8 MB
  unsigned short* vTb   = (unsigned short*)(W + 41943040); // 8 MB
  unsigned short* valsb = (unsigned short*)(W + 50331648); // 8 MB
  float*          projf = (float*)(W + 25165824);          // aliases qT+kT
  unsigned short* ff1b  = (unsigned short*)(W + 41943040); // aliases vT+vals
  unsigned short* wt    = (unsigned short*)(W + 58720256); // 4 MB
  float*          part  = (float*)(W + 62914560);          // 128 KB

  unsigned short* wt_qkv = wt;
  unsigned short* wt_o   = wt + 786432;
  unsigned short* wt_f1  = wt + 1048576;
  unsigned short* wt_f2  = wt + 1572864;

  inproj_kernel<<<8192, 512, 0, stream>>>(x, pos, pe, inW, inb, h, hb);

  for (int l = 0; l < 6; ++l) {
    wcast_kernel<<<512, 256, 0, stream>>>(
        qkvW + (size_t)l * 512 * 1536, oW + (size_t)l * 512 * 512,
        f1W + (size_t)l * 512 * 1024, f2W + (size_t)l * 1024 * 512,
        wt_qkv, wt_o, wt_f1, wt_f2);

    gemm_bf16<2><<<dim3(12, 64), 256, 0, stream>>>(
        hb, wt_qkv, qkvb + l * 1536, nullptr, nullptr, qTb, kTb, vTb,
        8192, 1536, 512);

    attn_mfma<<<1024, 256, 0, stream>>>(qTb, kTb, vTb, valsb);

    gemm_bf16<0><<<dim3(4, 64), 256, 0, stream>>>(
        valsb, wt_o, ob + l * 512, projf, nullptr, nullptr, nullptr, nullptr,
        8192, 512, 512);

    ln_residual<<<2048, 256, 0, stream>>>(h, projf, l1g + l * 512, l1b + l * 512, hb);

    gemm_bf16<1><<<dim3(8, 64), 256, 0, stream>>>(
        hb, wt_f1, f1b + l * 1024, nullptr, ff1b, nullptr, nullptr, nullptr,
        8192, 1024, 512);

    gemm_bf16<0><<<dim3(4, 64), 256, 0, stream>>>(
        ff1b, wt_f2, f2b + l * 512, projf, nullptr, nullptr, nullptr, nullptr,
        8192, 512, 1024);

    ln_residual<<<2048, 256, 0, stream>>>(h, projf, l2g + l * 512, l2b + l * 512, hb);
  }

  pool_kernel<<<64, 512, 0, stream>>>(h, part);
  head_kernel<<<8, 512, 0, stream>>>(part, o1W, o1b, og, obb, o2W, o2b, out);
}

// Round 3
// 1220.665 us; speedup vs baseline: 9.2756x; 1.0926x over previous
//
#include <hip/hip_runtime.h>
#include <cstddef>

#define EPS 1e-5f

typedef short bf16x8 __attribute__((ext_vector_type(8)));
typedef float f32x4 __attribute__((ext_vector_type(4)));
typedef unsigned short u16x8 __attribute__((ext_vector_type(8)));
typedef unsigned short u16x4 __attribute__((ext_vector_type(4)));

__device__ __forceinline__ unsigned short f2bf(float x) {
  unsigned u = __float_as_uint(x);
  return (unsigned short)((u + 0x7FFFu + ((u >> 16) & 1u)) >> 16);
}

__device__ __forceinline__ void gl2lds16(const unsigned short* g, unsigned short* l) {
  __builtin_amdgcn_global_load_lds(
      (const __attribute__((address_space(1))) unsigned int*)g,
      (__attribute__((address_space(3))) unsigned int*)l, 16, 0, 0);
}

// ---------------------------------------------------------------------------
// Input projection + PE gather -> h (fp32) and hb (bf16)
// ---------------------------------------------------------------------------
__global__ __launch_bounds__(512) void inproj_kernel(
    const float* __restrict__ x, const int* __restrict__ pos,
    const float* __restrict__ pe, const float* __restrict__ Wp,
    const float* __restrict__ bp, float* __restrict__ h,
    unsigned short* __restrict__ hb) {
  int t = blockIdx.x, d = threadIdx.x;
  __shared__ float xs[24];
  if (d < 24) xs[d] = x[(size_t)t * 24 + d];
  __syncthreads();
  float acc = bp[d] + pe[(size_t)pos[t] * 512 + d];
#pragma unroll
  for (int k = 0; k < 24; ++k) acc += xs[k] * Wp[k * 512 + d];
  h[(size_t)t * 512 + d] = acc;
  hb[(size_t)t * 512 + d] = f2bf(acc);
}

// ---------------------------------------------------------------------------
// Per-layer weight cast+transpose: W[K][N] fp32 -> Wt[N][K] bf16 (4 segments)
// ---------------------------------------------------------------------------
__global__ __launch_bounds__(256) void wcast_kernel(
    const float* __restrict__ qw, const float* __restrict__ ow,
    const float* __restrict__ f1w, const float* __restrict__ f2w,
    unsigned short* __restrict__ qd, unsigned short* __restrict__ od,
    unsigned short* __restrict__ f1d, unsigned short* __restrict__ f2d) {
  __shared__ float sm[64][65];
  int bid = blockIdx.x;
  const float* src; unsigned short* dst; int K, N, tile;
  if (bid < 192)      { src = qw;  dst = qd;  K = 512;  N = 1536; tile = bid; }
  else if (bid < 256) { src = ow;  dst = od;  K = 512;  N = 512;  tile = bid - 192; }
  else if (bid < 384) { src = f1w; dst = f1d; K = 512;  N = 1024; tile = bid - 256; }
  else                { src = f2w; dst = f2d; K = 1024; N = 512;  tile = bid - 384; }
  int nt = N >> 6;
  int tk = tile / nt, tn = tile % nt;
  int k0 = tk * 64, n0 = tn * 64;
  int tid = threadIdx.x;
#pragma unroll
  for (int it = 0; it < 16; ++it) {
    int idx = it * 256 + tid;
    int ki = idx >> 6, ni = idx & 63;
    sm[ki][ni] = src[(size_t)(k0 + ki) * N + n0 + ni];
  }
  __syncthreads();
#pragma unroll
  for (int it = 0; it < 16; ++it) {
    int idx = it * 256 + tid;
    int ni = idx >> 6, ki = idx & 63;
    dst[(size_t)(n0 + ni) * K + k0 + ki] = f2bf(sm[ki][ni]);
  }
}

// ---------------------------------------------------------------------------
// bf16 MFMA GEMM, 128x128 tile, BK=32, global_load_lds staging (m97-style).
// MODE 0: fp32 out. MODE 1: bf16 out + ReLU. MODE 2: qkv scatter (V transposed).
// ---------------------------------------------------------------------------
template <int MODE>
__global__ __launch_bounds__(256) void gemm_bf16(
    const unsigned short* __restrict__ A, const unsigned short* __restrict__ Bw,
    const float* __restrict__ bias, float* __restrict__ Cf,
    unsigned short* __restrict__ Cb, unsigned short* __restrict__ q_out,
    unsigned short* __restrict__ k_out, unsigned short* __restrict__ v_out,
    int M, int N, int K) {
  __shared__ unsigned short As[128 * 32];
  __shared__ unsigned short Bs[128 * 32];
  int tid = threadIdx.x;
  int w = tid >> 6, l = tid & 63;
  int wm = w >> 1, wn = w & 1;
  int cl = l & 15, kg = l >> 4;
  int n0 = blockIdx.x * 128, m0 = blockIdx.y * 128;
  f32x4 acc[4][4];
#pragma unroll
  for (int i = 0; i < 4; ++i)
#pragma unroll
    for (int j = 0; j < 4; ++j) acc[i][j] = f32x4{0.f, 0.f, 0.f, 0.f};

  const unsigned short* Ap = A + (size_t)m0 * K;
  const unsigned short* Bp = Bw + (size_t)n0 * K;

  for (int k0 = 0; k0 < K; k0 += 32) {
    __syncthreads();
#pragma unroll
    for (int c = 0; c < 2; ++c) {
      int idx = c * 256 + tid;
      int r = idx >> 2, kq = idx & 3;
      gl2lds16(Ap + (size_t)r * K + k0 + kq * 8, &As[(c * 256 + w * 64) * 8]);
      gl2lds16(Bp + (size_t)r * K + k0 + kq * 8, &Bs[(c * 256 + w * 64) * 8]);
    }
    __syncthreads();
    bf16x8 af[4], bfr[4];
#pragma unroll
    for (int i = 0; i < 4; ++i) {
      af[i]  = *(const bf16x8*)&As[(wm * 64 + i * 16 + cl) * 32 + kg * 8];
      bfr[i] = *(const bf16x8*)&Bs[(wn * 64 + i * 16 + cl) * 32 + kg * 8];
    }
#pragma unroll
    for (int i = 0; i < 4; ++i)
#pragma unroll
      for (int j = 0; j < 4; ++j)
        acc[i][j] = __builtin_amdgcn_mfma_f32_16x16x32_bf16(af[i], bfr[j], acc[i][j], 0, 0, 0);
  }

  int rl = kg * 4;
#pragma unroll
  for (int i = 0; i < 4; ++i) {
    int mbase = m0 + wm * 64 + i * 16 + rl;
#pragma unroll
    for (int j = 0; j < 4; ++j) {
      int col = n0 + wn * 64 + j * 16 + cl;
      float bv = bias[col];
      if (MODE == 0) {
#pragma unroll
        for (int r = 0; r < 4; ++r)
          Cf[(size_t)(mbase + r) * N + col] = acc[i][j][r] + bv;
      } else if (MODE == 1) {
#pragma unroll
        for (int r = 0; r < 4; ++r)
          Cb[(size_t)(mbase + r) * N + col] = f2bf(fmaxf(acc[i][j][r] + bv, 0.f));
      } else {
        int hh = col / 192;
        int rem = col - hh * 192;
        int which = rem >> 6, d = rem & 63;
        int b = mbase >> 10, s = mbase & 1023;
        if (which == 2) {
          // vT[bh][d][s]: 4 consecutive s -> one short4 write
          u16x4 pk;
#pragma unroll
          for (int r = 0; r < 4; ++r) pk[r] = f2bf(acc[i][j][r] + bv);
          *(u16x4*)&v_out[((size_t)((b * 8 + hh) * 64 + d)) * 1024 + s] = pk;
        } else {
          unsigned short* dst = (which == 0) ? q_out : k_out;
#pragma unroll
          for (int r = 0; r < 4; ++r)
            dst[(((size_t)(b * 8 + hh)) * 1024 + s + r) * 64 + d] = f2bf(acc[i][j][r] + bv);
        }
      }
    }
  }
}

// ---------------------------------------------------------------------------
// Flash attention v2: 8 waves x 16 q = 128 q/block, double-buffered K/V LDS,
// one barrier per 64-key chunk. qT/kT: [bh][s][64]; vT: [bh][d][s] (pre-T).
// ---------------------------------------------------------------------------
__global__ __launch_bounds__(512) void attn_mfma(
    const unsigned short* __restrict__ qT, const unsigned short* __restrict__ kT,
    const unsigned short* __restrict__ vT, unsigned short* __restrict__ valsb) {
  __shared__ unsigned short Ks[2][64 * 64];  // [k][d], byte ^ ((k&7)<<4)
  __shared__ unsigned short Vs[2][64 * 64];  // [d][k], byte ^ ((d&7)<<4)
  __shared__ unsigned short Ps[8][16 * 64];  // per-wave [q][k], byte ^ ((q&7)<<4)

  int bh = blockIdx.x >> 3;
  int qt = blockIdx.x & 7;
  int b = bh >> 3, h = bh & 7;
  int tid = threadIdx.x;
  int w = tid >> 6, l = tid & 63;
  int cl = l & 15, kg = l >> 4, rl = kg * 4;

  const unsigned short* kgb = kT + (size_t)bh * 65536;
  const unsigned short* vgb = vT + (size_t)bh * 65536;

  int q0 = qt * 128 + w * 16;
  const unsigned short* qbase = qT + ((size_t)bh * 1024 + q0) * 64;
  bf16x8 aq[2];
  aq[0] = *(const bf16x8*)(qbase + cl * 64 + kg * 8);
  aq[1] = *(const bf16x8*)(qbase + cl * 64 + 32 + kg * 8);

  int sk = tid >> 3, sa = tid & 7;
  int kboff = (sk * 128 + sa * 16) ^ ((sk & 7) << 4);

  const float C = 0.125f * 1.44269504f;  // scale * log2(e)

  float m2[4], lsum[4];
  f32x4 accO[4];
#pragma unroll
  for (int r = 0; r < 4; ++r) { m2[r] = -1e30f; lsum[r] = 0.f; }
#pragma unroll
  for (int df = 0; df < 4; ++df) accO[df] = f32x4{0.f, 0.f, 0.f, 0.f};

  char* Pw = (char*)&Ps[w][0];

  // prologue: stage chunk 0
  uint4 kv = *(const uint4*)(kgb + (size_t)sk * 64 + sa * 8);
  uint4 vv = *(const uint4*)(vgb + (size_t)sk * 1024 + sa * 8);
  *(uint4*)((char*)Ks[0] + kboff) = kv;
  *(uint4*)((char*)Vs[0] + kboff) = vv;
  __syncthreads();

  for (int c = 0; c < 16; ++c) {
    int cur = c & 1;
    if (c < 15) {  // issue next chunk's loads early (hide HBM under compute)
      kv = *(const uint4*)(kgb + (size_t)(c + 1) * 4096 + sk * 64 + sa * 8);
      vv = *(const uint4*)(vgb + (size_t)sk * 1024 + (c + 1) * 64 + sa * 8);
    }

    // QK^T: S[16q][64k] per wave
    f32x4 s[4];
#pragma unroll
    for (int kf = 0; kf < 4; ++kf) {
      s[kf] = f32x4{0.f, 0.f, 0.f, 0.f};
#pragma unroll
      for (int ks = 0; ks < 2; ++ks) {
        int row = kf * 16 + cl;
        int boff = (row * 128 + ks * 64 + kg * 16) ^ ((row & 7) << 4);
        bf16x8 bk = *(const bf16x8*)((char*)Ks[cur] + boff);
        s[kf] = __builtin_amdgcn_mfma_f32_16x16x32_bf16(aq[ks], bk, s[kf], 0, 0, 0);
      }
    }

    // online softmax in log2 domain
    float cm[4];
#pragma unroll
    for (int r = 0; r < 4; ++r)
      cm[r] = fmaxf(fmaxf(s[0][r], s[1][r]), fmaxf(s[2][r], s[3][r]));
#pragma unroll
    for (int off = 1; off < 16; off <<= 1)
#pragma unroll
      for (int r = 0; r < 4; ++r) cm[r] = fmaxf(cm[r], __shfl_xor(cm[r], off));

    float alpha[4];
#pragma unroll
    for (int r = 0; r < 4; ++r) {
      float mn = fmaxf(m2[r], cm[r] * C);
      alpha[r] = exp2f(m2[r] - mn);
      m2[r] = mn;
    }

    float rs[4] = {0.f, 0.f, 0.f, 0.f};
#pragma unroll
    for (int kf = 0; kf < 4; ++kf)
#pragma unroll
      for (int r = 0; r < 4; ++r) {
        float p = exp2f(s[kf][r] * C - m2[r]);
        rs[r] += p;
        int row = rl + r;
        int boff = (row * 128 + (kf * 16 + cl) * 2) ^ ((row & 7) << 4);
        *(unsigned short*)(Pw + boff) = f2bf(p);
      }
#pragma unroll
    for (int off = 1; off < 16; off <<= 1)
#pragma unroll
      for (int r = 0; r < 4; ++r) rs[r] += __shfl_xor(rs[r], off);
#pragma unroll
    for (int r = 0; r < 4; ++r) lsum[r] = lsum[r] * alpha[r] + rs[r];
#pragma unroll
    for (int df = 0; df < 4; ++df)
#pragma unroll
      for (int r = 0; r < 4; ++r) accO[df][r] *= alpha[r];

    // PV: O[16q][64d] += P @ V
#pragma unroll
    for (int ks = 0; ks < 2; ++ks) {
      int pboff = (cl * 128 + ks * 64 + kg * 16) ^ ((cl & 7) << 4);
      bf16x8 ap = *(const bf16x8*)(Pw + pboff);
#pragma unroll
      for (int df = 0; df < 4; ++df) {
        int d = df * 16 + cl;
        int vboff = (d * 128 + ks * 64 + kg * 16) ^ ((d & 7) << 4);
        bf16x8 bv = *(const bf16x8*)((char*)Vs[cur] + vboff);
        accO[df] = __builtin_amdgcn_mfma_f32_16x16x32_bf16(ap, bv, accO[df], 0, 0, 0);
      }
    }

    // write next chunk to the other buffer; single barrier per chunk
    if (c < 15) {
      *(uint4*)((char*)Ks[cur ^ 1] + kboff) = kv;
      *(uint4*)((char*)Vs[cur ^ 1] + kboff) = vv;
    }
    __syncthreads();
  }

  float inv[4];
#pragma unroll
  for (int r = 0; r < 4; ++r) inv[r] = 1.f / lsum[r];
#pragma unroll
  for (int df = 0; df < 4; ++df)
#pragma unroll
    for (int r = 0; r < 4; ++r) {
      int q = q0 + rl + r;
      int d = df * 16 + cl;
      valsb[(((size_t)b * 1024) + q) * 512 + h * 64 + d] = f2bf(accO[df][r] * inv[r]);
    }
}

// ---------------------------------------------------------------------------
// Fused residual + LayerNorm -> h (fp32) + hb (bf16). 4 rows/block.
// ---------------------------------------------------------------------------
__global__ __launch_bounds__(256) void ln_residual(
    float* __restrict__ h, const float* __restrict__ res,
    const float* __restrict__ g, const float* __restrict__ bb,
    unsigned short* __restrict__ hb) {
  int row = blockIdx.x * 4 + (threadIdx.x >> 6);
  int lane = threadIdx.x & 63;
  size_t base = (size_t)row * 512 + lane * 8;
  float4 v0 = *(const float4*)&h[base];
  float4 v1 = *(const float4*)&h[base + 4];
  float4 r0 = *(const float4*)&res[base];
  float4 r1 = *(const float4*)&res[base + 4];
  float xv[8];
  xv[0] = v0.x + r0.x; xv[1] = v0.y + r0.y; xv[2] = v0.z + r0.z; xv[3] = v0.w + r0.w;
  xv[4] = v1.x + r1.x; xv[5] = v1.y + r1.y; xv[6] = v1.z + r1.z; xv[7] = v1.w + r1.w;
  float s = 0.f, sq = 0.f;
#pragma unroll
  for (int i = 0; i < 8; ++i) { s += xv[i]; sq += xv[i] * xv[i]; }
#pragma unroll
  for (int off = 32; off; off >>= 1) { s += __shfl_xor(s, off); sq += __shfl_xor(sq, off); }
  float mu = s * (1.f / 512.f);
  float var = sq * (1.f / 512.f) - mu * mu;
  float rstd = rsqrtf(var + EPS);
  float4 g0 = *(const float4*)&g[lane * 8];
  float4 g1 = *(const float4*)&g[lane * 8 + 4];
  float4 b0 = *(const float4*)&bb[lane * 8];
  float4 b1 = *(const float4*)&bb[lane * 8 + 4];
  float o[8];
  o[0] = (xv[0] - mu) * rstd * g0.x + b0.x;
  o[1] = (xv[1] - mu) * rstd * g0.y + b0.y;
  o[2] = (xv[2] - mu) * rstd * g0.z + b0.z;
  o[3] = (xv[3] - mu) * rstd * g0.w + b0.w;
  o[4] = (xv[4] - mu) * rstd * g1.x + b1.x;
  o[5] = (xv[5] - mu) * rstd * g1.y + b1.y;
  o[6] = (xv[6] - mu) * rstd * g1.z + b1.z;
  o[7] = (xv[7] - mu) * rstd * g1.w + b1.w;
  *(float4*)&h[base] = make_float4(o[0], o[1], o[2], o[3]);
  *(float4*)&h[base + 4] = make_float4(o[4], o[5], o[6], o[7]);
  u16x8 hv;
#pragma unroll
  for (int i = 0; i < 8; ++i) hv[i] = f2bf(o[i]);
  *(u16x8*)&hb[base] = hv;
}

// ---------------------------------------------------------------------------
__global__ __launch_bounds__(512) void pool_kernel(
    const float* __restrict__ h, float* __restrict__ partial) {
  int b = blockIdx.x >> 3, c = blockIdx.x & 7, d = threadIdx.x;
  float s = 0.f;
  for (int t = 0; t < 128; ++t)
    s += h[((size_t)b * 1024 + c * 128 + t) * 512 + d];
  partial[(size_t)blockIdx.x * 512 + d] = s;
}

__global__ __launch_bounds__(512) void head_kernel(
    const float* __restrict__ partial, const float* __restrict__ W1,
    const float* __restrict__ b1, const float* __restrict__ g,
    const float* __restrict__ bb, const float* __restrict__ W2,
    const float* __restrict__ b2, float* __restrict__ out) {
  int b = blockIdx.x, tid = threadIdx.x;
  int wid = tid >> 6, lane = tid & 63;
  __shared__ float ps[512];
  __shared__ float red_s[8];
  __shared__ float red_q[8];
  float pv = 0.f;
#pragma unroll
  for (int c = 0; c < 8; ++c) pv += partial[((size_t)(b * 8 + c)) * 512 + tid];
  ps[tid] = pv * (1.f / 1024.f);
  __syncthreads();
  float acc = b1[tid];
  for (int k = 0; k < 512; ++k) acc += ps[k] * W1[(size_t)k * 512 + tid];
  float s = acc, sq = acc * acc;
#pragma unroll
  for (int off = 32; off; off >>= 1) { s += __shfl_xor(s, off); sq += __shfl_xor(sq, off); }
  if (lane == 0) { red_s[wid] = s; red_q[wid] = sq; }
  __syncthreads();
  float S = 0.f, Q = 0.f;
#pragma unroll
  for (int i = 0; i < 8; ++i) { S += red_s[i]; Q += red_q[i]; }
  float mu = S * (1.f / 512.f);
  float var = Q * (1.f / 512.f) - mu * mu;
  float rstd = rsqrtf(var + EPS);
  float z = (acc - mu) * rstd * g[tid] + bb[tid];
  float r = fmaxf(z, 0.f);
  float v = r * W2[tid];
#pragma unroll
  for (int off = 32; off; off >>= 1) v += __shfl_xor(v, off);
  __syncthreads();
  if (lane == 0) red_s[wid] = v;
  __syncthreads();
  if (tid == 0) {
    float t = 0.f;
#pragma unroll
    for (int i = 0; i < 8; ++i) t += red_s[i];
    out[b] = t + b2[0];
  }
}

// ---------------------------------------------------------------------------
extern "C" void kernel_launch(void* const* d_in, const int* in_sizes, int n_in,
                              void* d_out, int out_size, void* d_ws, size_t ws_size,
                              hipStream_t stream) {
  const float* x    = (const float*)d_in[0];
  const int*   pos  = (const int*)d_in[1];
  const float* pe   = (const float*)d_in[2];
  const float* inW  = (const float*)d_in[3];
  const float* inb  = (const float*)d_in[4];
  const float* qkvW = (const float*)d_in[5];
  const float* qkvb = (const float*)d_in[6];
  const float* oW   = (const float*)d_in[7];
  const float* ob   = (const float*)d_in[8];
  const float* f1W  = (const float*)d_in[9];
  const float* f1b  = (const float*)d_in[10];
  const float* f2W  = (const float*)d_in[11];
  const float* f2b  = (const float*)d_in[12];
  const float* l1g  = (const float*)d_in[13];
  const float* l1b  = (const float*)d_in[14];
  const float* l2g  = (const float*)d_in[15];
  const float* l2b  = (const float*)d_in[16];
  const float* o1W  = (const float*)d_in[17];
  const float* o1b  = (const float*)d_in[18];
  const float* og   = (const float*)d_in[19];
  const float* obb  = (const float*)d_in[20];
  const float* o2W  = (const float*)d_in[21];
  const float* o2b  = (const float*)d_in[22];
  float* out = (float*)d_out;

  char* W = (char*)d_ws;
  float*          h     = (float*)(W + 0);                 // 16 MB
  unsigned short* hb    = (unsigned short*)(W + 16777216); // 8 MB
  unsigned short* qTb   = (unsigned short*)(W + 25165824); // 8 MB
  unsigned short* kTb   = (unsigned short*)(W + 33554432); // 8 MB
  unsigned short* vTb   = (unsigned short*)(W + 41943040); // 8 MB [bh][d][s]
  unsigned short* valsb = (unsigned short*)(W + 50331648); // 8 MB
  float*          projf = (float*)(W + 25165824);          // aliases qT+kT
  unsigned short* ff1b  = (unsigned short*)(W + 41943040); // aliases vT+vals
  unsigned short* wt    = (unsigned short*)(W + 58720256); // 4 MB
  float*          part  = (float*)(W + 62914560);

  unsigned short* wt_qkv = wt;
  unsigned short* wt_o   = wt + 786432;
  unsigned short* wt_f1  = wt + 1048576;
  unsigned short* wt_f2  = wt + 1572864;

  inproj_kernel<<<8192, 512, 0, stream>>>(x, pos, pe, inW, inb, h, hb);

  for (int l = 0; l < 6; ++l) {
    wcast_kernel<<<512, 256, 0, stream>>>(
        qkvW + (size_t)l * 512 * 1536, oW + (size_t)l * 512 * 512,
        f1W + (size_t)l * 512 * 1024, f2W + (size_t)l * 1024 * 512,
        wt_qkv, wt_o, wt_f1, wt_f2);

    gemm_bf16<2><<<dim3(12, 64), 256, 0, stream>>>(
        hb, wt_qkv, qkvb + l * 1536, nullptr, nullptr, qTb, kTb, vTb,
        8192, 1536, 512);

    attn_mfma<<<512, 512, 0, stream>>>(qTb, kTb, vTb, valsb);

    gemm_bf16<0><<<dim3(4, 64), 256, 0, stream>>>(
        valsb, wt_o, ob + l * 512, projf, nullptr, nullptr, nullptr, nullptr,
        8192, 512, 512);

    ln_residual<<<2048, 256, 0, stream>>>(h, projf, l1g + l * 512, l1b + l * 512, hb);

    gemm_bf16<1><<<dim3(8, 64), 256, 0, stream>>>(
        hb, wt_f1, f1b + l * 1024, nullptr, ff1b, nullptr, nullptr, nullptr,
        8192, 1024, 512);

    gemm_bf16<0><<<dim3(4, 64), 256, 0, stream>>>(
        ff1b, wt_f2, f2b + l * 512, projf, nullptr, nullptr, nullptr, nullptr,
        8192, 512, 1024);

    ln_residual<<<2048, 256, 0, stream>>>(h, projf, l2g + l * 512, l2b + l * 512, hb);
  }

  pool_kernel<<<64, 512, 0, stream>>>(h, part);
  head_kernel<<<8, 512, 0, stream>>>(part, o1W, o1b, og, obb, o2W, o2b, out);
}

// Round 4
// 1155.729 us; speedup vs baseline: 9.7967x; 1.0562x over previous
//
#include <hip/hip_runtime.h>
#include <cstddef>

#define EPS 1e-5f

typedef short bf16x8 __attribute__((ext_vector_type(8)));
typedef float f32x4 __attribute__((ext_vector_type(4)));
typedef unsigned short u16x8 __attribute__((ext_vector_type(8)));
typedef unsigned short u16x4 __attribute__((ext_vector_type(4)));

__device__ __forceinline__ unsigned short f2bf(float x) {
  unsigned u = __float_as_uint(x);
  return (unsigned short)((u + 0x7FFFu + ((u >> 16) & 1u)) >> 16);
}

__device__ __forceinline__ void gl2lds16(const unsigned short* g, unsigned short* l) {
  __builtin_amdgcn_global_load_lds(
      (const __attribute__((address_space(1))) unsigned int*)g,
      (__attribute__((address_space(3))) unsigned int*)l, 16, 0, 0);
}

// ---------------------------------------------------------------------------
// Input projection + PE gather -> h (fp32) and hb (bf16)
// ---------------------------------------------------------------------------
__global__ __launch_bounds__(512) void inproj_kernel(
    const float* __restrict__ x, const int* __restrict__ pos,
    const float* __restrict__ pe, const float* __restrict__ Wp,
    const float* __restrict__ bp, float* __restrict__ h,
    unsigned short* __restrict__ hb) {
  int t = blockIdx.x, d = threadIdx.x;
  __shared__ float xs[24];
  if (d < 24) xs[d] = x[(size_t)t * 24 + d];
  __syncthreads();
  float acc = bp[d] + pe[(size_t)pos[t] * 512 + d];
#pragma unroll
  for (int k = 0; k < 24; ++k) acc += xs[k] * Wp[k * 512 + d];
  h[(size_t)t * 512 + d] = acc;
  hb[(size_t)t * 512 + d] = f2bf(acc);
}

// ---------------------------------------------------------------------------
// Per-layer weight cast+transpose: W[K][N] fp32 -> Wt[N][K] bf16 (4 segments)
// ---------------------------------------------------------------------------
__global__ __launch_bounds__(256) void wcast_kernel(
    const float* __restrict__ qw, const float* __restrict__ ow,
    const float* __restrict__ f1w, const float* __restrict__ f2w,
    unsigned short* __restrict__ qd, unsigned short* __restrict__ od,
    unsigned short* __restrict__ f1d, unsigned short* __restrict__ f2d) {
  __shared__ float sm[64][65];
  int bid = blockIdx.x;
  const float* src; unsigned short* dst; int K, N, tile;
  if (bid < 192)      { src = qw;  dst = qd;  K = 512;  N = 1536; tile = bid; }
  else if (bid < 256) { src = ow;  dst = od;  K = 512;  N = 512;  tile = bid - 192; }
  else if (bid < 384) { src = f1w; dst = f1d; K = 512;  N = 1024; tile = bid - 256; }
  else                { src = f2w; dst = f2d; K = 1024; N = 512;  tile = bid - 384; }
  int nt = N >> 6;
  int tk = tile / nt, tn = tile % nt;
  int k0 = tk * 64, n0 = tn * 64;
  int tid = threadIdx.x;
#pragma unroll
  for (int it = 0; it < 16; ++it) {
    int idx = it * 256 + tid;
    int ki = idx >> 6, ni = idx & 63;
    sm[ki][ni] = src[(size_t)(k0 + ki) * N + n0 + ni];
  }
  __syncthreads();
#pragma unroll
  for (int it = 0; it < 16; ++it) {
    int idx = it * 256 + tid;
    int ni = idx >> 6, ki = idx & 63;
    dst[(size_t)(n0 + ni) * K + k0 + ki] = f2bf(sm[ki][ni]);
  }
}

// ---------------------------------------------------------------------------
// bf16 MFMA GEMM, 128x128 tile, BK=64, global_load_lds with pre-swizzled
// source (LDS dest linear, read side XOR ^((row&7)<<4) -> conflict-free).
// MODE 0: fp32 out. MODE 1: bf16 out + ReLU. MODE 2: qkv scatter (V pre-T).
// ---------------------------------------------------------------------------
template <int MODE>
__global__ __launch_bounds__(256) void gemm_bf16(
    const unsigned short* __restrict__ A, const unsigned short* __restrict__ Bw,
    const float* __restrict__ bias, float* __restrict__ Cf,
    unsigned short* __restrict__ Cb, unsigned short* __restrict__ q_out,
    unsigned short* __restrict__ k_out, unsigned short* __restrict__ v_out,
    int M, int N, int K) {
  __shared__ unsigned short As[128 * 64];
  __shared__ unsigned short Bs[128 * 64];
  int tid = threadIdx.x;
  int w = tid >> 6, l = tid & 63;
  int wm = w >> 1, wn = w & 1;
  int cl = l & 15, kg = l >> 4;
  int n0 = blockIdx.x * 128, m0 = blockIdx.y * 128;
  f32x4 acc[4][4];
#pragma unroll
  for (int i = 0; i < 4; ++i)
#pragma unroll
    for (int j = 0; j < 4; ++j) acc[i][j] = f32x4{0.f, 0.f, 0.f, 0.f};

  const unsigned short* Ap = A + (size_t)m0 * K;
  const unsigned short* Bp = Bw + (size_t)n0 * K;

  for (int k0 = 0; k0 < K; k0 += 64) {
    __syncthreads();
#pragma unroll
    for (int c = 0; c < 4; ++c) {
      int idx = c * 256 + tid;
      int r = idx >> 3;
      int kq = (idx & 7) ^ (r & 7);  // pre-swizzled source granule
      gl2lds16(Ap + (size_t)r * K + k0 + kq * 8, &As[(c * 256 + w * 64) * 8]);
    }
#pragma unroll
    for (int c = 0; c < 4; ++c) {
      int idx = c * 256 + tid;
      int r = idx >> 3;
      int kq = (idx & 7) ^ (r & 7);
      gl2lds16(Bp + (size_t)r * K + k0 + kq * 8, &Bs[(c * 256 + w * 64) * 8]);
    }
    __syncthreads();
    bf16x8 af[4][2], bfr[4][2];
    int key = (cl & 7) << 4;
#pragma unroll
    for (int i = 0; i < 4; ++i) {
      int rowa = wm * 64 + i * 16 + cl;
      int rowb = wn * 64 + i * 16 + cl;
#pragma unroll
      for (int s2 = 0; s2 < 2; ++s2) {
        af[i][s2]  = *(const bf16x8*)((char*)As + ((rowa * 128 + s2 * 64 + kg * 16) ^ key));
        bfr[i][s2] = *(const bf16x8*)((char*)Bs + ((rowb * 128 + s2 * 64 + kg * 16) ^ key));
      }
    }
#pragma unroll
    for (int i = 0; i < 4; ++i)
#pragma unroll
      for (int j = 0; j < 4; ++j) {
        acc[i][j] = __builtin_amdgcn_mfma_f32_16x16x32_bf16(af[i][0], bfr[j][0], acc[i][j], 0, 0, 0);
        acc[i][j] = __builtin_amdgcn_mfma_f32_16x16x32_bf16(af[i][1], bfr[j][1], acc[i][j], 0, 0, 0);
      }
  }

  int rl = kg * 4;
#pragma unroll
  for (int i = 0; i < 4; ++i) {
    int mbase = m0 + wm * 64 + i * 16 + rl;
#pragma unroll
    for (int j = 0; j < 4; ++j) {
      int col = n0 + wn * 64 + j * 16 + cl;
      float bv = bias[col];
      if (MODE == 0) {
#pragma unroll
        for (int r = 0; r < 4; ++r)
          Cf[(size_t)(mbase + r) * N + col] = acc[i][j][r] + bv;
      } else if (MODE == 1) {
#pragma unroll
        for (int r = 0; r < 4; ++r)
          Cb[(size_t)(mbase + r) * N + col] = f2bf(fmaxf(acc[i][j][r] + bv, 0.f));
      } else {
        int hh = col / 192;
        int rem = col - hh * 192;
        int which = rem >> 6, d = rem & 63;
        int b = mbase >> 10, s = mbase & 1023;
        if (which == 2) {
          u16x4 pk;
#pragma unroll
          for (int r = 0; r < 4; ++r) pk[r] = f2bf(acc[i][j][r] + bv);
          *(u16x4*)&v_out[((size_t)((b * 8 + hh) * 64 + d)) * 1024 + s] = pk;
        } else {
          unsigned short* dst = (which == 0) ? q_out : k_out;
#pragma unroll
          for (int r = 0; r < 4; ++r)
            dst[(((size_t)(b * 8 + hh)) * 1024 + s + r) * 64 + d] = f2bf(acc[i][j][r] + bv);
        }
      }
    }
  }
}

// ---------------------------------------------------------------------------
// Flash attention v3: 8 waves x 16 q, KVBLK=128, single-buffer LDS (64 KB),
// reg-prefetch (T14), deferred max (T13) + per-lane deferred lsum reduce.
// qT/kT: [bh][s][64]; vT: [bh][d][s] (pre-transposed).
// ---------------------------------------------------------------------------
__global__ __launch_bounds__(512) void attn_mfma(
    const unsigned short* __restrict__ qT, const unsigned short* __restrict__ kT,
    const unsigned short* __restrict__ vT, unsigned short* __restrict__ valsb) {
  __shared__ unsigned short Ks[128 * 64];    // [k][d], byte ^ ((k&7)<<4)
  __shared__ unsigned short Vs[64 * 128];    // [d][k], byte ^ ((d&7)<<4)
  __shared__ unsigned short Ps[8][16 * 128]; // per-wave [q][k], byte ^ ((q&7)<<4)

  int bh = blockIdx.x >> 3;
  int qt = blockIdx.x & 7;
  int b = bh >> 3, h = bh & 7;
  int tid = threadIdx.x;
  int w = tid >> 6, l = tid & 63;
  int cl = l & 15, kg = l >> 4, rl = kg * 4;

  const unsigned short* kgb = kT + (size_t)bh * 65536;
  const unsigned short* vgb = vT + (size_t)bh * 65536;

  int q0 = qt * 128 + w * 16;
  const unsigned short* qbase = qT + ((size_t)bh * 1024 + q0) * 64;
  bf16x8 aq[2];
  aq[0] = *(const bf16x8*)(qbase + cl * 64 + kg * 8);
  aq[1] = *(const bf16x8*)(qbase + cl * 64 + 32 + kg * 8);

  // staging maps
  int kk = tid >> 3, ka = tid & 7;   // K rows kk, kk+64; 16B col ka
  int vd = tid >> 4, vs = tid & 15;  // V rows vd, vd+32; 16B col vs
  int kb0 = (kk * 128 + ka * 16) ^ ((kk & 7) << 4);
  int kb1 = kb0 + 64 * 128;
  int vb0 = (vd * 256 + vs * 16) ^ ((vd & 7) << 4);
  int vb1 = vb0 + 32 * 256;

  const float C = 0.125f * 1.44269504f;  // scale * log2(e)
  float m2[4], lsum[4];
  f32x4 accO[4];
#pragma unroll
  for (int r = 0; r < 4; ++r) { m2[r] = -1e30f; lsum[r] = 0.f; }
#pragma unroll
  for (int df = 0; df < 4; ++df) accO[df] = f32x4{0.f, 0.f, 0.f, 0.f};

  char* Pw = (char*)&Ps[w][0];

  // prologue: chunk 0 into regs
  uint4 kr0 = *(const uint4*)(kgb + (size_t)kk * 64 + ka * 8);
  uint4 kr1 = *(const uint4*)(kgb + (size_t)(kk + 64) * 64 + ka * 8);
  uint4 vr0 = *(const uint4*)(vgb + (size_t)vd * 1024 + vs * 8);
  uint4 vr1 = *(const uint4*)(vgb + (size_t)(vd + 32) * 1024 + vs * 8);

  for (int c = 0; c < 8; ++c) {
    __syncthreads();  // previous chunk's compute done -> LDS free
    *(uint4*)((char*)Ks + kb0) = kr0;
    *(uint4*)((char*)Ks + kb1) = kr1;
    *(uint4*)((char*)Vs + vb0) = vr0;
    *(uint4*)((char*)Vs + vb1) = vr1;
    if (c < 7) {  // issue next chunk loads; latency hides under compute
      kr0 = *(const uint4*)(kgb + (size_t)((c + 1) * 128 + kk) * 64 + ka * 8);
      kr1 = *(const uint4*)(kgb + (size_t)((c + 1) * 128 + kk + 64) * 64 + ka * 8);
      vr0 = *(const uint4*)(vgb + (size_t)vd * 1024 + (c + 1) * 128 + vs * 8);
      vr1 = *(const uint4*)(vgb + (size_t)(vd + 32) * 1024 + (c + 1) * 128 + vs * 8);
    }
    __syncthreads();  // LDS ready

    // QK^T: S[16q][128k] per wave
    f32x4 s[8];
    int keyq = (cl & 7) << 4;
#pragma unroll
    for (int kf = 0; kf < 8; ++kf) {
      s[kf] = f32x4{0.f, 0.f, 0.f, 0.f};
      int row = kf * 16 + cl;
#pragma unroll
      for (int ks = 0; ks < 2; ++ks) {
        int boff = (row * 128 + ks * 64 + kg * 16) ^ keyq;
        s[kf] = __builtin_amdgcn_mfma_f32_16x16x32_bf16(
            aq[ks], *(const bf16x8*)((char*)Ks + boff), s[kf], 0, 0, 0);
      }
    }

    // per-lane local max
    float lmax[4];
#pragma unroll
    for (int r = 0; r < 4; ++r) {
      float a0 = fmaxf(fmaxf(s[0][r], s[1][r]), fmaxf(s[2][r], s[3][r]));
      float a1 = fmaxf(fmaxf(s[4][r], s[5][r]), fmaxf(s[6][r], s[7][r]));
      lmax[r] = fmaxf(a0, a1);
    }
    float need = fmaxf(fmaxf(lmax[0] * C - m2[0], lmax[1] * C - m2[1]),
                       fmaxf(lmax[2] * C - m2[2], lmax[3] * C - m2[3]));
    if (!__all(need <= 8.0f)) {
      // slow path: full row-max tree + rescale (rare after chunk 0)
      float cm[4];
#pragma unroll
      for (int r = 0; r < 4; ++r) cm[r] = lmax[r];
#pragma unroll
      for (int off = 1; off < 16; off <<= 1)
#pragma unroll
        for (int r = 0; r < 4; ++r) cm[r] = fmaxf(cm[r], __shfl_xor(cm[r], off));
#pragma unroll
      for (int r = 0; r < 4; ++r) {
        float mn = fmaxf(m2[r], cm[r] * C);
        float alpha = exp2f(m2[r] - mn);
        m2[r] = mn;
        lsum[r] *= alpha;
        accO[0][r] *= alpha; accO[1][r] *= alpha;
        accO[2][r] *= alpha; accO[3][r] *= alpha;
      }
    }

    // P = exp2(s*C - m2); per-lane partial lsum; cheap-rounded bf16 store
#pragma unroll
    for (int kf = 0; kf < 8; ++kf) {
#pragma unroll
      for (int r = 0; r < 4; ++r) {
        float p = exp2f(s[kf][r] * C - m2[r]);
        lsum[r] += p;
        int row = rl + r;
        int boff = (row * 256 + (kf * 16 + cl) * 2) ^ ((row & 7) << 4);
        *(unsigned short*)(Pw + boff) =
            (unsigned short)((__float_as_uint(p) + 0x8000u) >> 16);
      }
    }

    // PV: O[16q][64d] += P @ V
#pragma unroll
    for (int ks = 0; ks < 4; ++ks) {
      int pboff = (cl * 256 + ks * 64 + kg * 16) ^ ((cl & 7) << 4);
      bf16x8 ap = *(const bf16x8*)(Pw + pboff);
#pragma unroll
      for (int df = 0; df < 4; ++df) {
        int d = df * 16 + cl;
        int vboff = (d * 256 + ks * 64 + kg * 16) ^ ((d & 7) << 4);
        accO[df] = __builtin_amdgcn_mfma_f32_16x16x32_bf16(
            ap, *(const bf16x8*)((char*)Vs + vboff), accO[df], 0, 0, 0);
      }
    }
  }

  // deferred lsum reduce across the 16-lane row group
#pragma unroll
  for (int off = 1; off < 16; off <<= 1)
#pragma unroll
    for (int r = 0; r < 4; ++r) lsum[r] += __shfl_xor(lsum[r], off);

  float inv[4];
#pragma unroll
  for (int r = 0; r < 4; ++r) inv[r] = 1.f / lsum[r];
#pragma unroll
  for (int df = 0; df < 4; ++df)
#pragma unroll
    for (int r = 0; r < 4; ++r) {
      int q = q0 + rl + r;
      int d = df * 16 + cl;
      valsb[(((size_t)b * 1024) + q) * 512 + h * 64 + d] = f2bf(accO[df][r] * inv[r]);
    }
}

// ---------------------------------------------------------------------------
// Fused residual + LayerNorm -> h (fp32) + hb (bf16). 4 rows/block.
// ---------------------------------------------------------------------------
__global__ __launch_bounds__(256) void ln_residual(
    float* __restrict__ h, const float* __restrict__ res,
    const float* __restrict__ g, const float* __restrict__ bb,
    unsigned short* __restrict__ hb) {
  int row = blockIdx.x * 4 + (threadIdx.x >> 6);
  int lane = threadIdx.x & 63;
  size_t base = (size_t)row * 512 + lane * 8;
  float4 v0 = *(const float4*)&h[base];
  float4 v1 = *(const float4*)&h[base + 4];
  float4 r0 = *(const float4*)&res[base];
  float4 r1 = *(const float4*)&res[base + 4];
  float xv[8];
  xv[0] = v0.x + r0.x; xv[1] = v0.y + r0.y; xv[2] = v0.z + r0.z; xv[3] = v0.w + r0.w;
  xv[4] = v1.x + r1.x; xv[5] = v1.y + r1.y; xv[6] = v1.z + r1.z; xv[7] = v1.w + r1.w;
  float s = 0.f, sq = 0.f;
#pragma unroll
  for (int i = 0; i < 8; ++i) { s += xv[i]; sq += xv[i] * xv[i]; }
#pragma unroll
  for (int off = 32; off; off >>= 1) { s += __shfl_xor(s, off); sq += __shfl_xor(sq, off); }
  float mu = s * (1.f / 512.f);
  float var = sq * (1.f / 512.f) - mu * mu;
  float rstd = rsqrtf(var + EPS);
  float4 g0 = *(const float4*)&g[lane * 8];
  float4 g1 = *(const float4*)&g[lane * 8 + 4];
  float4 b0 = *(const float4*)&bb[lane * 8];
  float4 b1 = *(const float4*)&bb[lane * 8 + 4];
  float o[8];
  o[0] = (xv[0] - mu) * rstd * g0.x + b0.x;
  o[1] = (xv[1] - mu) * rstd * g0.y + b0.y;
  o[2] = (xv[2] - mu) * rstd * g0.z + b0.z;
  o[3] = (xv[3] - mu) * rstd * g0.w + b0.w;
  o[4] = (xv[4] - mu) * rstd * g1.x + b1.x;
  o[5] = (xv[5] - mu) * rstd * g1.y + b1.y;
  o[6] = (xv[6] - mu) * rstd * g1.z + b1.z;
  o[7] = (xv[7] - mu) * rstd * g1.w + b1.w;
  *(float4*)&h[base] = make_float4(o[0], o[1], o[2], o[3]);
  *(float4*)&h[base + 4] = make_float4(o[4], o[5], o[6], o[7]);
  u16x8 hv;
#pragma unroll
  for (int i = 0; i < 8; ++i) hv[i] = f2bf(o[i]);
  *(u16x8*)&hb[base] = hv;
}

// ---------------------------------------------------------------------------
__global__ __launch_bounds__(512) void pool_kernel(
    const float* __restrict__ h, float* __restrict__ partial) {
  int b = blockIdx.x >> 3, c = blockIdx.x & 7, d = threadIdx.x;
  float s = 0.f;
  for (int t = 0; t < 128; ++t)
    s += h[((size_t)b * 1024 + c * 128 + t) * 512 + d];
  partial[(size_t)blockIdx.x * 512 + d] = s;
}

__global__ __launch_bounds__(512) void head_kernel(
    const float* __restrict__ partial, const float* __restrict__ W1,
    const float* __restrict__ b1, const float* __restrict__ g,
    const float* __restrict__ bb, const float* __restrict__ W2,
    const float* __restrict__ b2, float* __restrict__ out) {
  int b = blockIdx.x, tid = threadIdx.x;
  int wid = tid >> 6, lane = tid & 63;
  __shared__ float ps[512];
  __shared__ float red_s[8];
  __shared__ float red_q[8];
  float pv = 0.f;
#pragma unroll
  for (int c = 0; c < 8; ++c) pv += partial[((size_t)(b * 8 + c)) * 512 + tid];
  ps[tid] = pv * (1.f / 1024.f);
  __syncthreads();
  float acc = b1[tid];
  for (int k = 0; k < 512; ++k) acc += ps[k] * W1[(size_t)k * 512 + tid];
  float s = acc, sq = acc * acc;
#pragma unroll
  for (int off = 32; off; off >>= 1) { s += __shfl_xor(s, off); sq += __shfl_xor(sq, off); }
  if (lane == 0) { red_s[wid] = s; red_q[wid] = sq; }
  __syncthreads();
  float S = 0.f, Q = 0.f;
#pragma unroll
  for (int i = 0; i < 8; ++i) { S += red_s[i]; Q += red_q[i]; }
  float mu = S * (1.f / 512.f);
  float var = Q * (1.f / 512.f) - mu * mu;
  float rstd = rsqrtf(var + EPS);
  float z = (acc - mu) * rstd * g[tid] + bb[tid];
  float r = fmaxf(z, 0.f);
  float v = r * W2[tid];
#pragma unroll
  for (int off = 32; off; off >>= 1) v += __shfl_xor(v, off);
  __syncthreads();
  if (lane == 0) red_s[wid] = v;
  __syncthreads();
  if (tid == 0) {
    float t = 0.f;
#pragma unroll
    for (int i = 0; i < 8; ++i) t += red_s[i];
    out[b] = t + b2[0];
  }
}

// ---------------------------------------------------------------------------
extern "C" void kernel_launch(void* const* d_in, const int* in_sizes, int n_in,
                              void* d_out, int out_size, void* d_ws, size_t ws_size,
                              hipStream_t stream) {
  const float* x    = (const float*)d_in[0];
  const int*   pos  = (const int*)d_in[1];
  const float* pe   = (const float*)d_in[2];
  const float* inW  = (const float*)d_in[3];
  const float* inb  = (const float*)d_in[4];
  const float* qkvW = (const float*)d_in[5];
  const float* qkvb = (const float*)d_in[6];
  const float* oW   = (const float*)d_in[7];
  const float* ob   = (const float*)d_in[8];
  const float* f1W  = (const float*)d_in[9];
  const float* f1b  = (const float*)d_in[10];
  const float* f2W  = (const float*)d_in[11];
  const float* f2b  = (const float*)d_in[12];
  const float* l1g  = (const float*)d_in[13];
  const float* l1b  = (const float*)d_in[14];
  const float* l2g  = (const float*)d_in[15];
  const float* l2b  = (const float*)d_in[16];
  const float* o1W  = (const float*)d_in[17];
  const float* o1b  = (const float*)d_in[18];
  const float* og   = (const float*)d_in[19];
  const float* obb  = (const float*)d_in[20];
  const float* o2W  = (const float*)d_in[21];
  const float* o2b  = (const float*)d_in[22];
  float* out = (float*)d_out;

  char* W = (char*)d_ws;
  float*          h     = (float*)(W + 0);                 // 16 MB
  unsigned short* hb    = (unsigned short*)(W + 16777216); // 8 MB
  unsigned short* qTb   = (unsigned short*)(W + 25165824); // 8 MB
  unsigned short* kTb   = (unsigned short*)(W + 33554432); // 8 MB
  unsigned short* vTb   = (unsigned short*)(W + 41943040); // 8 MB [bh][d][s]
  unsigned short* valsb = (unsigned short*)(W + 50331648); // 8 MB
  float*          projf = (float*)(W + 25165824);          // aliases qT+kT
  unsigned short* ff1b  = (unsigned short*)(W + 41943040); // aliases vT+vals
  unsigned short* wt    = (unsigned short*)(W + 58720256); // 4 MB
  float*          part  = (float*)(W + 62914560);

  unsigned short* wt_qkv = wt;
  unsigned short* wt_o   = wt + 786432;
  unsigned short* wt_f1  = wt + 1048576;
  unsigned short* wt_f2  = wt + 1572864;

  inproj_kernel<<<8192, 512, 0, stream>>>(x, pos, pe, inW, inb, h, hb);

  for (int l = 0; l < 6; ++l) {
    wcast_kernel<<<512, 256, 0, stream>>>(
        qkvW + (size_t)l * 512 * 1536, oW + (size_t)l * 512 * 512,
        f1W + (size_t)l * 512 * 1024, f2W + (size_t)l * 1024 * 512,
        wt_qkv, wt_o, wt_f1, wt_f2);

    gemm_bf16<2><<<dim3(12, 64), 256, 0, stream>>>(
        hb, wt_qkv, qkvb + l * 1536, nullptr, nullptr, qTb, kTb, vTb,
        8192, 1536, 512);

    attn_mfma<<<512, 512, 0, stream>>>(qTb, kTb, vTb, valsb);

    gemm_bf16<0><<<dim3(4, 64), 256, 0, stream>>>(
        valsb, wt_o, ob + l * 512, projf, nullptr, nullptr, nullptr, nullptr,
        8192, 512, 512);

    ln_residual<<<2048, 256, 0, stream>>>(h, projf, l1g + l * 512, l1b + l * 512, hb);

    gemm_bf16<1><<<dim3(8, 64), 256, 0, stream>>>(
        hb, wt_f1, f1b + l * 1024, nullptr, ff1b, nullptr, nullptr, nullptr,
        8192, 1024, 512);

    gemm_bf16<0><<<dim3(4, 64), 256, 0, stream>>>(
        ff1b, wt_f2, f2b + l * 512, projf, nullptr, nullptr, nullptr, nullptr,
        8192, 512, 1024);

    ln_residual<<<2048, 256, 0, stream>>>(h, projf, l2g + l * 512, l2b + l * 512, hb);
  }

  pool_kernel<<<64, 512, 0, stream>>>(h, part);
  head_kernel<<<8, 512, 0, stream>>>(part, o1W, o1b, og, obb, o2W, o2b, out);
}

// Round 8
// 1022.583 us; speedup vs baseline: 11.0723x; 1.1302x over previous
//
#include <hip/hip_runtime.h>
#include <cstddef>

#define EPS 1e-5f

typedef short bf16x8 __attribute__((ext_vector_type(8)));
typedef float f32x4 __attribute__((ext_vector_type(4)));
typedef unsigned short u16x8 __attribute__((ext_vector_type(8)));
typedef unsigned short u16x4 __attribute__((ext_vector_type(4)));

__device__ __forceinline__ unsigned short f2bf(float x) {
  unsigned u = __float_as_uint(x);
  return (unsigned short)((u + 0x7FFFu + ((u >> 16) & 1u)) >> 16);
}
__device__ __forceinline__ float bf2f(unsigned short v) {
  return __uint_as_float((unsigned)v << 16);
}

__device__ __forceinline__ void gl2lds16(const unsigned short* g, unsigned short* l) {
  __builtin_amdgcn_global_load_lds(
      (const __attribute__((address_space(1))) unsigned int*)g,
      (__attribute__((address_space(3))) unsigned int*)l, 16, 0, 0);
}

// ---------------------------------------------------------------------------
// Input projection + PE gather -> h (fp32) and hb (bf16)
// ---------------------------------------------------------------------------
__global__ __launch_bounds__(512) void inproj_kernel(
    const float* __restrict__ x, const int* __restrict__ pos,
    const float* __restrict__ pe, const float* __restrict__ Wp,
    const float* __restrict__ bp, float* __restrict__ h,
    unsigned short* __restrict__ hb) {
  int t = blockIdx.x, d = threadIdx.x;
  __shared__ float xs[24];
  if (d < 24) xs[d] = x[(size_t)t * 24 + d];
  __syncthreads();
  float acc = bp[d] + pe[(size_t)pos[t] * 512 + d];
#pragma unroll
  for (int k = 0; k < 24; ++k) acc += xs[k] * Wp[k * 512 + d];
  h[(size_t)t * 512 + d] = acc;
  hb[(size_t)t * 512 + d] = f2bf(acc);
}

// ---------------------------------------------------------------------------
// Per-layer weight cast+transpose: W[K][N] fp32 -> Wt[N][K] bf16 (4 segments)
// ---------------------------------------------------------------------------
__global__ __launch_bounds__(256) void wcast_kernel(
    const float* __restrict__ qw, const float* __restrict__ ow,
    const float* __restrict__ f1w, const float* __restrict__ f2w,
    unsigned short* __restrict__ qd, unsigned short* __restrict__ od,
    unsigned short* __restrict__ f1d, unsigned short* __restrict__ f2d) {
  __shared__ float sm[64][65];
  int bid = blockIdx.x;
  const float* src; unsigned short* dst; int K, N, tile;
  if (bid < 192)      { src = qw;  dst = qd;  K = 512;  N = 1536; tile = bid; }
  else if (bid < 256) { src = ow;  dst = od;  K = 512;  N = 512;  tile = bid - 192; }
  else if (bid < 384) { src = f1w; dst = f1d; K = 512;  N = 1024; tile = bid - 256; }
  else                { src = f2w; dst = f2d; K = 1024; N = 512;  tile = bid - 384; }
  int nt = N >> 6;
  int tk = tile / nt, tn = tile % nt;
  int k0 = tk * 64, n0 = tn * 64;
  int tid = threadIdx.x;
#pragma unroll
  for (int it = 0; it < 16; ++it) {
    int idx = it * 256 + tid;
    int ki = idx >> 6, ni = idx & 63;
    sm[ki][ni] = src[(size_t)(k0 + ki) * N + n0 + ni];
  }
  __syncthreads();
#pragma unroll
  for (int it = 0; it < 16; ++it) {
    int idx = it * 256 + tid;
    int ni = idx >> 6, ki = idx & 63;
    dst[(size_t)(n0 + ni) * K + k0 + ki] = f2bf(sm[ki][ni]);
  }
}

// ---------------------------------------------------------------------------
// bf16 MFMA GEMM, BMx128 tile, BK=64, double-buffered gl2lds staging with a
// SINGLE __syncthreads per K-step placed after compute -> DMA overlaps MFMA.
// Read side XOR ^((row&7)<<4); source pre-swizzled so LDS dest stays linear.
// MODE 1: bf16 out + ReLU. MODE 2: qkv head-major scatter (V pre-transposed).
// MODE 3: bf16 out, no ReLU.
// ---------------------------------------------------------------------------
template <int MODE, int BM>
__global__ __launch_bounds__(256) void gemm_bf16(
    const unsigned short* __restrict__ A, const unsigned short* __restrict__ Bw,
    const float* __restrict__ bias,
    unsigned short* __restrict__ Cb, unsigned short* __restrict__ q_out,
    unsigned short* __restrict__ k_out, unsigned short* __restrict__ v_out,
    int M, int N, int K) {
  constexpr int MI = BM / 32;  // m-frags per wave
  __shared__ unsigned short As[2][BM * 64];
  __shared__ unsigned short Bs[2][128 * 64];
  int tid = threadIdx.x;
  int w = tid >> 6, l = tid & 63;
  int wm = w >> 1, wn = w & 1;
  int cl = l & 15, kg = l >> 4;
  int n0 = blockIdx.x * 128, m0 = blockIdx.y * BM;
  f32x4 acc[MI][4];
#pragma unroll
  for (int i = 0; i < MI; ++i)
#pragma unroll
    for (int j = 0; j < 4; ++j) acc[i][j] = f32x4{0.f, 0.f, 0.f, 0.f};

  const unsigned short* Ap = A + (size_t)m0 * K;
  const unsigned short* Bp = Bw + (size_t)n0 * K;

  auto stage = [&](int buf, int t) {
#pragma unroll
    for (int p = 0; p < BM / 32; ++p) {
      int idx = p * 256 + tid;
      int r = idx >> 3;
      int kq = (idx & 7) ^ (r & 7);
      gl2lds16(Ap + (size_t)r * K + t * 64 + kq * 8, &As[buf][(p * 256 + w * 64) * 8]);
    }
#pragma unroll
    for (int p = 0; p < 4; ++p) {
      int idx = p * 256 + tid;
      int r = idx >> 3;
      int kq = (idx & 7) ^ (r & 7);
      gl2lds16(Bp + (size_t)r * K + t * 64 + kq * 8, &Bs[buf][(p * 256 + w * 64) * 8]);
    }
  };

  stage(0, 0);
  __syncthreads();
  int nk = K >> 6;
  for (int t = 0; t < nk; ++t) {
    int cur = t & 1;
    if (t + 1 < nk) stage(cur ^ 1, t + 1);  // DMA flies under compute
    bf16x8 af[MI][2], bfr[4][2];
    int key = (cl & 7) << 4;
#pragma unroll
    for (int i = 0; i < MI; ++i) {
      int rowa = wm * (BM / 2) + i * 16 + cl;
#pragma unroll
      for (int s2 = 0; s2 < 2; ++s2)
        af[i][s2] = *(const bf16x8*)((char*)As[cur] + ((rowa * 128 + s2 * 64 + kg * 16) ^ key));
    }
#pragma unroll
    for (int j = 0; j < 4; ++j) {
      int rowb = wn * 64 + j * 16 + cl;
#pragma unroll
      for (int s2 = 0; s2 < 2; ++s2)
        bfr[j][s2] = *(const bf16x8*)((char*)Bs[cur] + ((rowb * 128 + s2 * 64 + kg * 16) ^ key));
    }
#pragma unroll
    for (int i = 0; i < MI; ++i)
#pragma unroll
      for (int j = 0; j < 4; ++j) {
        acc[i][j] = __builtin_amdgcn_mfma_f32_16x16x32_bf16(af[i][0], bfr[j][0], acc[i][j], 0, 0, 0);
        acc[i][j] = __builtin_amdgcn_mfma_f32_16x16x32_bf16(af[i][1], bfr[j][1], acc[i][j], 0, 0, 0);
      }
    __syncthreads();  // drains DMA (next buf ready) + all reads of cur done
  }

  int rl = kg * 4;
#pragma unroll
  for (int i = 0; i < MI; ++i) {
    int mbase = m0 + wm * (BM / 2) + i * 16 + rl;
#pragma unroll
    for (int j = 0; j < 4; ++j) {
      int col = n0 + wn * 64 + j * 16 + cl;
      float bv = bias[col];
      if (MODE == 1) {
#pragma unroll
        for (int r = 0; r < 4; ++r)
          Cb[(size_t)(mbase + r) * N + col] = f2bf(fmaxf(acc[i][j][r] + bv, 0.f));
      } else if (MODE == 3) {
#pragma unroll
        for (int r = 0; r < 4; ++r)
          Cb[(size_t)(mbase + r) * N + col] = f2bf(acc[i][j][r] + bv);
      } else {
        int hh = col / 192;
        int rem = col - hh * 192;
        int which = rem >> 6, d = rem & 63;
        int b = mbase >> 10, s = mbase & 1023;
        if (which == 2) {
          u16x4 pk;
#pragma unroll
          for (int r = 0; r < 4; ++r) pk[r] = f2bf(acc[i][j][r] + bv);
          *(u16x4*)&v_out[((size_t)((b * 8 + hh) * 64 + d)) * 1024 + s] = pk;
        } else {
          unsigned short* dst = (which == 0) ? q_out : k_out;
#pragma unroll
          for (int r = 0; r < 4; ++r)
            dst[(((size_t)(b * 8 + hh)) * 1024 + s + r) * 64 + d] = f2bf(acc[i][j][r] + bv);
        }
      }
    }
  }
}

// ---------------------------------------------------------------------------
// Flash attention v4: 256 threads (4 waves x 16 q), grid 1024 decoded
// bh = blockIdx&63 so all q-tiles of one head share an XCD (L2-local K/V).
// KVBLK=64, gl2lds double-buffer, ONE __syncthreads per chunk (after
// compute). Deferred-max softmax (T13) + deferred lsum reduce.
// qT/kT: [bh][s][64]; vT: [bh][d][s] (pre-transposed).
// ---------------------------------------------------------------------------
__global__ __launch_bounds__(256) void attn_mfma(
    const unsigned short* __restrict__ qT, const unsigned short* __restrict__ kT,
    const unsigned short* __restrict__ vT, unsigned short* __restrict__ valsb) {
  __shared__ unsigned short Ks[2][64 * 64];  // [k][d], byte ^ ((k&7)<<4)
  __shared__ unsigned short Vs[2][64 * 64];  // [d][k], byte ^ ((d&7)<<4)
  __shared__ unsigned short Ps[4][16 * 64];  // per-wave [q][k], byte ^ ((q&7)<<4)

  int bh = blockIdx.x & 63;
  int qt = blockIdx.x >> 6;
  int b = bh >> 3, h = bh & 7;
  int tid = threadIdx.x;
  int w = tid >> 6, l = tid & 63;
  int cl = l & 15, kg = l >> 4, rl = kg * 4;

  const unsigned short* kgb = kT + (size_t)bh * 65536;
  const unsigned short* vgb = vT + (size_t)bh * 65536;

  int q0 = qt * 64 + w * 16;
  const unsigned short* qbase = qT + ((size_t)bh * 1024 + q0) * 64;
  bf16x8 aq[2];
  aq[0] = *(const bf16x8*)(qbase + cl * 64 + kg * 8);
  aq[1] = *(const bf16x8*)(qbase + cl * 64 + 32 + kg * 8);

  auto stage = [&](int buf, int c) {
#pragma unroll
    for (int p = 0; p < 2; ++p) {
      int idx = p * 256 + tid;
      int r = idx >> 3;
      int kq = (idx & 7) ^ (r & 7);
      gl2lds16(kgb + ((size_t)(c * 64 + r)) * 64 + kq * 8, &Ks[buf][(p * 256 + w * 64) * 8]);
    }
#pragma unroll
    for (int p = 0; p < 2; ++p) {
      int idx = p * 256 + tid;
      int r = idx >> 3;
      int kq = (idx & 7) ^ (r & 7);
      gl2lds16(vgb + (size_t)r * 1024 + c * 64 + kq * 8, &Vs[buf][(p * 256 + w * 64) * 8]);
    }
  };

  const float C = 0.125f * 1.44269504f;  // scale * log2(e)
  float m2[4], lsum[4];
  f32x4 accO[4];
#pragma unroll
  for (int r = 0; r < 4; ++r) { m2[r] = -1e30f; lsum[r] = 0.f; }
#pragma unroll
  for (int df = 0; df < 4; ++df) accO[df] = f32x4{0.f, 0.f, 0.f, 0.f};

  char* Pw = (char*)&Ps[w][0];

  stage(0, 0);
  __syncthreads();

  for (int c = 0; c < 16; ++c) {
    int cur = c & 1;
    if (c < 15) stage(cur ^ 1, c + 1);  // DMA flies under compute

    // QK^T: S[16q][64k] per wave
    f32x4 s[4];
#pragma unroll
    for (int kf = 0; kf < 4; ++kf) {
      s[kf] = f32x4{0.f, 0.f, 0.f, 0.f};
      int row = kf * 16 + cl;
#pragma unroll
      for (int ks = 0; ks < 2; ++ks) {
        int boff = (row * 128 + ks * 64 + kg * 16) ^ ((row & 7) << 4);
        s[kf] = __builtin_amdgcn_mfma_f32_16x16x32_bf16(
            aq[ks], *(const bf16x8*)((char*)Ks[cur] + boff), s[kf], 0, 0, 0);
      }
    }

    // deferred-max online softmax
    float lmax[4];
#pragma unroll
    for (int r = 0; r < 4; ++r)
      lmax[r] = fmaxf(fmaxf(s[0][r], s[1][r]), fmaxf(s[2][r], s[3][r]));
    float need = fmaxf(fmaxf(lmax[0] * C - m2[0], lmax[1] * C - m2[1]),
                       fmaxf(lmax[2] * C - m2[2], lmax[3] * C - m2[3]));
    if (!__all(need <= 8.0f)) {
      float cm[4];
#pragma unroll
      for (int r = 0; r < 4; ++r) cm[r] = lmax[r];
#pragma unroll
      for (int off = 1; off < 16; off <<= 1)
#pragma unroll
        for (int r = 0; r < 4; ++r) cm[r] = fmaxf(cm[r], __shfl_xor(cm[r], off));
#pragma unroll
      for (int r = 0; r < 4; ++r) {
        float mn = fmaxf(m2[r], cm[r] * C);
        float alpha = exp2f(m2[r] - mn);
        m2[r] = mn;
        lsum[r] *= alpha;
        accO[0][r] *= alpha; accO[1][r] *= alpha;
        accO[2][r] *= alpha; accO[3][r] *= alpha;
      }
    }

    // P = exp2(s*C - m2); per-lane partial lsum; cheap-rounded bf16 store
#pragma unroll
    for (int kf = 0; kf < 4; ++kf) {
#pragma unroll
      for (int r = 0; r < 4; ++r) {
        float p = exp2f(s[kf][r] * C - m2[r]);
        lsum[r] += p;
        int row = rl + r;
        int boff = (row * 128 + (kf * 16 + cl) * 2) ^ ((row & 7) << 4);
        *(unsigned short*)(Pw + boff) =
            (unsigned short)((__float_as_uint(p) + 0x8000u) >> 16);
      }
    }

    // PV: O[16q][64d] += P @ V
#pragma unroll
    for (int ks = 0; ks < 2; ++ks) {
      int pboff = (cl * 128 + ks * 64 + kg * 16) ^ ((cl & 7) << 4);
      bf16x8 ap = *(const bf16x8*)(Pw + pboff);
#pragma unroll
      for (int df = 0; df < 4; ++df) {
        int d = df * 16 + cl;
        int vboff = (d * 128 + ks * 64 + kg * 16) ^ ((d & 7) << 4);
        accO[df] = __builtin_amdgcn_mfma_f32_16x16x32_bf16(
            ap, *(const bf16x8*)((char*)Vs[cur] + vboff), accO[df], 0, 0, 0);
      }
    }

    __syncthreads();  // DMA for next buf drained + all reads of cur done
  }

  // deferred lsum reduce across the 16-lane row group
#pragma unroll
  for (int off = 1; off < 16; off <<= 1)
#pragma unroll
    for (int r = 0; r < 4; ++r) lsum[r] += __shfl_xor(lsum[r], off);

  float inv[4];
#pragma unroll
  for (int r = 0; r < 4; ++r) inv[r] = 1.f / lsum[r];
#pragma unroll
  for (int df = 0; df < 4; ++df)
#pragma unroll
    for (int r = 0; r < 4; ++r) {
      int q = q0 + rl + r;
      int d = df * 16 + cl;
      valsb[(((size_t)b * 1024) + q) * 512 + h * 64 + d] = f2bf(accO[df][r] * inv[r]);
    }
}

// ---------------------------------------------------------------------------
// Fused residual + LayerNorm: h = LN(h + res_bf16) -> h (fp32) + hb (bf16).
// ---------------------------------------------------------------------------
__global__ __launch_bounds__(256) void ln_residual(
    float* __restrict__ h, const unsigned short* __restrict__ res,
    const float* __restrict__ g, const float* __restrict__ bb,
    unsigned short* __restrict__ hb) {
  int row = blockIdx.x * 4 + (threadIdx.x >> 6);
  int lane = threadIdx.x & 63;
  size_t base = (size_t)row * 512 + lane * 8;
  float4 v0 = *(const float4*)&h[base];
  float4 v1 = *(const float4*)&h[base + 4];
  u16x8 rv = *(const u16x8*)&res[base];
  float xv[8];
  xv[0] = v0.x + bf2f(rv[0]); xv[1] = v0.y + bf2f(rv[1]);
  xv[2] = v0.z + bf2f(rv[2]); xv[3] = v0.w + bf2f(rv[3]);
  xv[4] = v1.x + bf2f(rv[4]); xv[5] = v1.y + bf2f(rv[5]);
  xv[6] = v1.z + bf2f(rv[6]); xv[7] = v1.w + bf2f(rv[7]);
  float s = 0.f, sq = 0.f;
#pragma unroll
  for (int i = 0; i < 8; ++i) { s += xv[i]; sq += xv[i] * xv[i]; }
#pragma unroll
  for (int off = 32; off; off >>= 1) { s += __shfl_xor(s, off); sq += __shfl_xor(sq, off); }
  float mu = s * (1.f / 512.f);
  float var = sq * (1.f / 512.f) - mu * mu;
  float rstd = rsqrtf(var + EPS);
  float4 g0 = *(const float4*)&g[lane * 8];
  float4 g1 = *(const float4*)&g[lane * 8 + 4];
  float4 b0 = *(const float4*)&bb[lane * 8];
  float4 b1 = *(const float4*)&bb[lane * 8 + 4];
  float o[8];
  o[0] = (xv[0] - mu) * rstd * g0.x + b0.x;
  o[1] = (xv[1] - mu) * rstd * g0.y + b0.y;
  o[2] = (xv[2] - mu) * rstd * g0.z + b0.z;
  o[3] = (xv[3] - mu) * rstd * g0.w + b0.w;
  o[4] = (xv[4] - mu) * rstd * g1.x + b1.x;
  o[5] = (xv[5] - mu) * rstd * g1.y + b1.y;
  o[6] = (xv[6] - mu) * rstd * g1.z + b1.z;
  o[7] = (xv[7] - mu) * rstd * g1.w + b1.w;
  *(float4*)&h[base] = make_float4(o[0], o[1], o[2], o[3]);
  *(float4*)&h[base + 4] = make_float4(o[4], o[5], o[6], o[7]);
  u16x8 hv;
#pragma unroll
  for (int i = 0; i < 8; ++i) hv[i] = f2bf(o[i]);
  *(u16x8*)&hb[base] = hv;
}

// ---------------------------------------------------------------------------
__global__ __launch_bounds__(512) void pool_kernel(
    const float* __restrict__ h, float* __restrict__ partial) {
  int b = blockIdx.x >> 3, c = blockIdx.x & 7, d = threadIdx.x;
  float s = 0.f;
  for (int t = 0; t < 128; ++t)
    s += h[((size_t)b * 1024 + c * 128 + t) * 512 + d];
  partial[(size_t)blockIdx.x * 512 + d] = s;
}

__global__ __launch_bounds__(512) void head_kernel(
    const float* __restrict__ partial, const float* __restrict__ W1,
    const float* __restrict__ b1, const float* __restrict__ g,
    const float* __restrict__ bb, const float* __restrict__ W2,
    const float* __restrict__ b2, float* __restrict__ out) {
  int b = blockIdx.x, tid = threadIdx.x;
  int wid = tid >> 6, lane = tid & 63;
  __shared__ float ps[512];
  __shared__ float red_s[8];
  __shared__ float red_q[8];
  float pv = 0.f;
#pragma unroll
  for (int c = 0; c < 8; ++c) pv += partial[((size_t)(b * 8 + c)) * 512 + tid];
  ps[tid] = pv * (1.f / 1024.f);
  __syncthreads();
  float acc = b1[tid];
  for (int k = 0; k < 512; ++k) acc += ps[k] * W1[(size_t)k * 512 + tid];
  float s = acc, sq = acc * acc;
#pragma unroll
  for (int off = 32; off; off >>= 1) { s += __shfl_xor(s, off); sq += __shfl_xor(sq, off); }
  if (lane == 0) { red_s[wid] = s; red_q[wid] = sq; }
  __syncthreads();
  float S = 0.f, Q = 0.f;
#pragma unroll
  for (int i = 0; i < 8; ++i) { S += red_s[i]; Q += red_q[i]; }
  float mu = S * (1.f / 512.f);
  float var = Q * (1.f / 512.f) - mu * mu;
  float rstd = rsqrtf(var + EPS);
  float z = (acc - mu) * rstd * g[tid] + bb[tid];
  float r = fmaxf(z, 0.f);
  float v = r * W2[tid];
#pragma unroll
  for (int off = 32; off; off >>= 1) v += __shfl_xor(v, off);
  __syncthreads();
  if (lane == 0) red_s[wid] = v;
  __syncthreads();
  if (tid == 0) {
    float t = 0.f;
#pragma unroll
    for (int i = 0; i < 8; ++i) t += red_s[i];
    out[b] = t + b2[0];
  }
}

// ---------------------------------------------------------------------------
extern "C" void kernel_launch(void* const* d_in, const int* in_sizes, int n_in,
                              void* d_out, int out_size, void* d_ws, size_t ws_size,
                              hipStream_t stream) {
  const float* x    = (const float*)d_in[0];
  const int*   pos  = (const int*)d_in[1];
  const float* pe   = (const float*)d_in[2];
  const float* inW  = (const float*)d_in[3];
  const float* inb  = (const float*)d_in[4];
  const float* qkvW = (const float*)d_in[5];
  const float* qkvb = (const float*)d_in[6];
  const float* oW   = (const float*)d_in[7];
  const float* ob   = (const float*)d_in[8];
  const float* f1W  = (const float*)d_in[9];
  const float* f1b  = (const float*)d_in[10];
  const float* f2W  = (const float*)d_in[11];
  const float* f2b  = (const float*)d_in[12];
  const float* l1g  = (const float*)d_in[13];
  const float* l1b  = (const float*)d_in[14];
  const float* l2g  = (const float*)d_in[15];
  const float* l2b  = (const float*)d_in[16];
  const float* o1W  = (const float*)d_in[17];
  const float* o1b  = (const float*)d_in[18];
  const float* og   = (const float*)d_in[19];
  const float* obb  = (const float*)d_in[20];
  const float* o2W  = (const float*)d_in[21];
  const float* o2b  = (const float*)d_in[22];
  float* out = (float*)d_out;

  char* W = (char*)d_ws;
  float*          h     = (float*)(W + 0);                 // 16 MB
  unsigned short* hb    = (unsigned short*)(W + 16777216); // 8 MB
  unsigned short* qTb   = (unsigned short*)(W + 25165824); // 8 MB
  unsigned short* kTb   = (unsigned short*)(W + 33554432); // 8 MB
  unsigned short* vTb   = (unsigned short*)(W + 41943040); // 8 MB [bh][d][s]
  unsigned short* valsb = (unsigned short*)(W + 50331648); // 8 MB
  unsigned short* projb = (unsigned short*)(W + 25165824); // aliases qT
  unsigned short* ff1b  = (unsigned short*)(W + 41943040); // aliases vT+vals
  unsigned short* wt    = (unsigned short*)(W + 58720256); // 4 MB
  float*          part  = (float*)(W + 62914560);

  unsigned short* wt_qkv = wt;
  unsigned short* wt_o   = wt + 786432;
  unsigned short* wt_f1  = wt + 1048576;
  unsigned short* wt_f2  = wt + 1572864;

  inproj_kernel<<<8192, 512, 0, stream>>>(x, pos, pe, inW, inb, h, hb);

  for (int l = 0; l < 6; ++l) {
    wcast_kernel<<<512, 256, 0, stream>>>(
        qkvW + (size_t)l * 512 * 1536, oW + (size_t)l * 512 * 512,
        f1W + (size_t)l * 512 * 1024, f2W + (size_t)l * 1024 * 512,
        wt_qkv, wt_o, wt_f1, wt_f2);

    gemm_bf16<2, 128><<<dim3(12, 64), 256, 0, stream>>>(
        hb, wt_qkv, qkvb + l * 1536, nullptr, qTb, kTb, vTb, 8192, 1536, 512);

    attn_mfma<<<1024, 256, 0, stream>>>(qTb, kTb, vTb, valsb);

    gemm_bf16<3, 64><<<dim3(4, 128), 256, 0, stream>>>(
        valsb, wt_o, ob + l * 512, projb, nullptr, nullptr, nullptr, 8192, 512, 512);

    ln_residual<<<2048, 256, 0, stream>>>(h, projb, l1g + l * 512, l1b + l * 512, hb);

    gemm_bf16<1, 128><<<dim3(8, 64), 256, 0, stream>>>(
        hb, wt_f1, f1b + l * 1024, ff1b, nullptr, nullptr, nullptr, 8192, 1024, 512);

    gemm_bf16<3, 64><<<dim3(4, 128), 256, 0, stream>>>(
        ff1b, wt_f2, f2b + l * 512, projb, nullptr, nullptr, nullptr, 8192, 512, 1024);

    ln_residual<<<2048, 256, 0, stream>>>(h, projb, l2g + l * 512, l2b + l * 512, hb);
  }

  pool_kernel<<<64, 512, 0, stream>>>(h, part);
  head_kernel<<<8, 512, 0, stream>>>(part, o1W, o1b, og, obb, o2W, o2b, out);
}

// Round 9
// 1004.196 us; speedup vs baseline: 11.2751x; 1.0183x over previous
//
#include <hip/hip_runtime.h>
#include <cstddef>

#define EPS 1e-5f

typedef short bf16x8 __attribute__((ext_vector_type(8)));
typedef float f32x4 __attribute__((ext_vector_type(4)));
typedef unsigned short u16x8 __attribute__((ext_vector_type(8)));
typedef unsigned short u16x4 __attribute__((ext_vector_type(4)));

__device__ __forceinline__ unsigned short f2bf(float x) {
  unsigned u = __float_as_uint(x);
  return (unsigned short)((u + 0x7FFFu + ((u >> 16) & 1u)) >> 16);
}
__device__ __forceinline__ float bf2f(unsigned short v) {
  return __uint_as_float((unsigned)v << 16);
}

__device__ __forceinline__ void gl2lds16(const unsigned short* g, unsigned short* l) {
  __builtin_amdgcn_global_load_lds(
      (const __attribute__((address_space(1))) unsigned int*)g,
      (__attribute__((address_space(3))) unsigned int*)l, 16, 0, 0);
}

// ---------------------------------------------------------------------------
// Input projection + PE gather -> h (fp32) and hb (bf16)
// ---------------------------------------------------------------------------
__global__ __launch_bounds__(512) void inproj_kernel(
    const float* __restrict__ x, const int* __restrict__ pos,
    const float* __restrict__ pe, const float* __restrict__ Wp,
    const float* __restrict__ bp, float* __restrict__ h,
    unsigned short* __restrict__ hb) {
  int t = blockIdx.x, d = threadIdx.x;
  __shared__ float xs[24];
  if (d < 24) xs[d] = x[(size_t)t * 24 + d];
  __syncthreads();
  float acc = bp[d] + pe[(size_t)pos[t] * 512 + d];
#pragma unroll
  for (int k = 0; k < 24; ++k) acc += xs[k] * Wp[k * 512 + d];
  h[(size_t)t * 512 + d] = acc;
  hb[(size_t)t * 512 + d] = f2bf(acc);
}

// ---------------------------------------------------------------------------
// Per-layer weight cast+transpose: W[K][N] fp32 -> Wt[N][K] bf16 (4 segments)
// ---------------------------------------------------------------------------
__global__ __launch_bounds__(256) void wcast_kernel(
    const float* __restrict__ qw, const float* __restrict__ ow,
    const float* __restrict__ f1w, const float* __restrict__ f2w,
    unsigned short* __restrict__ qd, unsigned short* __restrict__ od,
    unsigned short* __restrict__ f1d, unsigned short* __restrict__ f2d) {
  __shared__ float sm[64][65];
  int bid = blockIdx.x;
  const float* src; unsigned short* dst; int K, N, tile;
  if (bid < 192)      { src = qw;  dst = qd;  K = 512;  N = 1536; tile = bid; }
  else if (bid < 256) { src = ow;  dst = od;  K = 512;  N = 512;  tile = bid - 192; }
  else if (bid < 384) { src = f1w; dst = f1d; K = 512;  N = 1024; tile = bid - 256; }
  else                { src = f2w; dst = f2d; K = 1024; N = 512;  tile = bid - 384; }
  int nt = N >> 6;
  int tk = tile / nt, tn = tile % nt;
  int k0 = tk * 64, n0 = tn * 64;
  int tid = threadIdx.x;
#pragma unroll
  for (int it = 0; it < 16; ++it) {
    int idx = it * 256 + tid;
    int ki = idx >> 6, ni = idx & 63;
    sm[ki][ni] = src[(size_t)(k0 + ki) * N + n0 + ni];
  }
  __syncthreads();
#pragma unroll
  for (int it = 0; it < 16; ++it) {
    int idx = it * 256 + tid;
    int ni = idx >> 6, ki = idx & 63;
    dst[(size_t)(n0 + ni) * K + k0 + ki] = f2bf(sm[ki][ni]);
  }
}

// ---------------------------------------------------------------------------
// bf16 MFMA GEMM, BMx128 tile, BK=64, double-buffered gl2lds staging with a
// SINGLE __syncthreads per K-step placed after compute -> DMA overlaps MFMA.
// Read side XOR ^((row&7)<<4); source pre-swizzled so LDS dest stays linear.
// 1-D grid with XCD-locality swizzle (T1): XCD c owns a contiguous y-chunk,
// so A-panels are fetched once per XCD and stay L2-resident.
// MODE 1: bf16 out + ReLU. MODE 2: qkv head-major scatter (V pre-transposed).
// MODE 3: bf16 out, no ReLU.
// ---------------------------------------------------------------------------
template <int MODE, int BM, int NX>
__global__ __launch_bounds__(256) void gemm_bf16(
    const unsigned short* __restrict__ A, const unsigned short* __restrict__ Bw,
    const float* __restrict__ bias,
    unsigned short* __restrict__ Cb, unsigned short* __restrict__ q_out,
    unsigned short* __restrict__ k_out, unsigned short* __restrict__ v_out,
    int M, int N, int K) {
  constexpr int MI = BM / 32;  // m-frags per wave
  __shared__ unsigned short As[2][BM * 64];
  __shared__ unsigned short Bs[2][128 * 64];
  // XCD swizzle: nwg % 8 == 0 for all our grids -> bijective (guide T1)
  int nwg = gridDim.x;
  int cpx = nwg >> 3;
  int wgid = (blockIdx.x & 7) * cpx + (blockIdx.x >> 3);
  int tx = wgid % NX, ty = wgid / NX;
  int tid = threadIdx.x;
  int w = tid >> 6, l = tid & 63;
  int wm = w >> 1, wn = w & 1;
  int cl = l & 15, kg = l >> 4;
  int n0 = tx * 128, m0 = ty * BM;
  f32x4 acc[MI][4];
#pragma unroll
  for (int i = 0; i < MI; ++i)
#pragma unroll
    for (int j = 0; j < 4; ++j) acc[i][j] = f32x4{0.f, 0.f, 0.f, 0.f};

  const unsigned short* Ap = A + (size_t)m0 * K;
  const unsigned short* Bp = Bw + (size_t)n0 * K;

  auto stage = [&](int buf, int t) {
#pragma unroll
    for (int p = 0; p < BM / 32; ++p) {
      int idx = p * 256 + tid;
      int r = idx >> 3;
      int kq = (idx & 7) ^ (r & 7);
      gl2lds16(Ap + (size_t)r * K + t * 64 + kq * 8, &As[buf][(p * 256 + w * 64) * 8]);
    }
#pragma unroll
    for (int p = 0; p < 4; ++p) {
      int idx = p * 256 + tid;
      int r = idx >> 3;
      int kq = (idx & 7) ^ (r & 7);
      gl2lds16(Bp + (size_t)r * K + t * 64 + kq * 8, &Bs[buf][(p * 256 + w * 64) * 8]);
    }
  };

  stage(0, 0);
  __syncthreads();
  int nk = K >> 6;
  for (int t = 0; t < nk; ++t) {
    int cur = t & 1;
    if (t + 1 < nk) stage(cur ^ 1, t + 1);  // DMA flies under compute
    bf16x8 af[MI][2], bfr[4][2];
    int key = (cl & 7) << 4;
#pragma unroll
    for (int i = 0; i < MI; ++i) {
      int rowa = wm * (BM / 2) + i * 16 + cl;
#pragma unroll
      for (int s2 = 0; s2 < 2; ++s2)
        af[i][s2] = *(const bf16x8*)((char*)As[cur] + ((rowa * 128 + s2 * 64 + kg * 16) ^ key));
    }
#pragma unroll
    for (int j = 0; j < 4; ++j) {
      int rowb = wn * 64 + j * 16 + cl;
#pragma unroll
      for (int s2 = 0; s2 < 2; ++s2)
        bfr[j][s2] = *(const bf16x8*)((char*)Bs[cur] + ((rowb * 128 + s2 * 64 + kg * 16) ^ key));
    }
#pragma unroll
    for (int i = 0; i < MI; ++i)
#pragma unroll
      for (int j = 0; j < 4; ++j) {
        acc[i][j] = __builtin_amdgcn_mfma_f32_16x16x32_bf16(af[i][0], bfr[j][0], acc[i][j], 0, 0, 0);
        acc[i][j] = __builtin_amdgcn_mfma_f32_16x16x32_bf16(af[i][1], bfr[j][1], acc[i][j], 0, 0, 0);
      }
    __syncthreads();  // drains DMA (next buf ready) + all reads of cur done
  }

  int rl = kg * 4;
#pragma unroll
  for (int i = 0; i < MI; ++i) {
    int mbase = m0 + wm * (BM / 2) + i * 16 + rl;
#pragma unroll
    for (int j = 0; j < 4; ++j) {
      int col = n0 + wn * 64 + j * 16 + cl;
      float bv = bias[col];
      if (MODE == 1) {
#pragma unroll
        for (int r = 0; r < 4; ++r)
          Cb[(size_t)(mbase + r) * N + col] = f2bf(fmaxf(acc[i][j][r] + bv, 0.f));
      } else if (MODE == 3) {
#pragma unroll
        for (int r = 0; r < 4; ++r)
          Cb[(size_t)(mbase + r) * N + col] = f2bf(acc[i][j][r] + bv);
      } else {
        int hh = col / 192;
        int rem = col - hh * 192;
        int which = rem >> 6, d = rem & 63;
        int b = mbase >> 10, s = mbase & 1023;
        if (which == 2) {
          u16x4 pk;
#pragma unroll
          for (int r = 0; r < 4; ++r) pk[r] = f2bf(acc[i][j][r] + bv);
          *(u16x4*)&v_out[((size_t)((b * 8 + hh) * 64 + d)) * 1024 + s] = pk;
        } else {
          unsigned short* dst = (which == 0) ? q_out : k_out;
#pragma unroll
          for (int r = 0; r < 4; ++r)
            dst[(((size_t)(b * 8 + hh)) * 1024 + s + r) * 64 + d] = f2bf(acc[i][j][r] + bv);
        }
      }
    }
  }
}

// ---------------------------------------------------------------------------
// Flash attention v5: 256 threads (4 waves x 16 q), grid 1024 decoded
// bh = blockIdx&63 so all q-tiles of one head share an XCD (L2-local K/V).
// KVBLK=64, gl2lds double-buffer, ONE __syncthreads per chunk (after
// compute). Deferred-max softmax (T13) + deferred lsum reduce.
// T5: setprio(1) around MFMA clusters (m191: +4-7% attn).
// qT/kT: [bh][s][64]; vT: [bh][d][s] (pre-transposed).
// ---------------------------------------------------------------------------
__global__ __launch_bounds__(256) void attn_mfma(
    const unsigned short* __restrict__ qT, const unsigned short* __restrict__ kT,
    const unsigned short* __restrict__ vT, unsigned short* __restrict__ valsb) {
  __shared__ unsigned short Ks[2][64 * 64];  // [k][d], byte ^ ((k&7)<<4)
  __shared__ unsigned short Vs[2][64 * 64];  // [d][k], byte ^ ((d&7)<<4)
  __shared__ unsigned short Ps[4][16 * 64];  // per-wave [q][k], byte ^ ((q&7)<<4)

  int bh = blockIdx.x & 63;
  int qt = blockIdx.x >> 6;
  int b = bh >> 3, h = bh & 7;
  int tid = threadIdx.x;
  int w = tid >> 6, l = tid & 63;
  int cl = l & 15, kg = l >> 4, rl = kg * 4;

  const unsigned short* kgb = kT + (size_t)bh * 65536;
  const unsigned short* vgb = vT + (size_t)bh * 65536;

  int q0 = qt * 64 + w * 16;
  const unsigned short* qbase = qT + ((size_t)bh * 1024 + q0) * 64;
  bf16x8 aq[2];
  aq[0] = *(const bf16x8*)(qbase + cl * 64 + kg * 8);
  aq[1] = *(const bf16x8*)(qbase + cl * 64 + 32 + kg * 8);

  auto stage = [&](int buf, int c) {
#pragma unroll
    for (int p = 0; p < 2; ++p) {
      int idx = p * 256 + tid;
      int r = idx >> 3;
      int kq = (idx & 7) ^ (r & 7);
      gl2lds16(kgb + ((size_t)(c * 64 + r)) * 64 + kq * 8, &Ks[buf][(p * 256 + w * 64) * 8]);
    }
#pragma unroll
    for (int p = 0; p < 2; ++p) {
      int idx = p * 256 + tid;
      int r = idx >> 3;
      int kq = (idx & 7) ^ (r & 7);
      gl2lds16(vgb + (size_t)r * 1024 + c * 64 + kq * 8, &Vs[buf][(p * 256 + w * 64) * 8]);
    }
  };

  const float C = 0.125f * 1.44269504f;  // scale * log2(e)
  float m2[4], lsum[4];
  f32x4 accO[4];
#pragma unroll
  for (int r = 0; r < 4; ++r) { m2[r] = -1e30f; lsum[r] = 0.f; }
#pragma unroll
  for (int df = 0; df < 4; ++df) accO[df] = f32x4{0.f, 0.f, 0.f, 0.f};

  char* Pw = (char*)&Ps[w][0];

  stage(0, 0);
  __syncthreads();

  for (int c = 0; c < 16; ++c) {
    int cur = c & 1;
    if (c < 15) stage(cur ^ 1, c + 1);  // DMA flies under compute

    // QK^T: S[16q][64k] per wave
    f32x4 s[4];
    __builtin_amdgcn_s_setprio(1);
#pragma unroll
    for (int kf = 0; kf < 4; ++kf) {
      s[kf] = f32x4{0.f, 0.f, 0.f, 0.f};
      int row = kf * 16 + cl;
#pragma unroll
      for (int ks = 0; ks < 2; ++ks) {
        int boff = (row * 128 + ks * 64 + kg * 16) ^ ((row & 7) << 4);
        s[kf] = __builtin_amdgcn_mfma_f32_16x16x32_bf16(
            aq[ks], *(const bf16x8*)((char*)Ks[cur] + boff), s[kf], 0, 0, 0);
      }
    }
    __builtin_amdgcn_s_setprio(0);

    // deferred-max online softmax
    float lmax[4];
#pragma unroll
    for (int r = 0; r < 4; ++r)
      lmax[r] = fmaxf(fmaxf(s[0][r], s[1][r]), fmaxf(s[2][r], s[3][r]));
    float need = fmaxf(fmaxf(lmax[0] * C - m2[0], lmax[1] * C - m2[1]),
                       fmaxf(lmax[2] * C - m2[2], lmax[3] * C - m2[3]));
    if (!__all(need <= 8.0f)) {
      float cm[4];
#pragma unroll
      for (int r = 0; r < 4; ++r) cm[r] = lmax[r];
#pragma unroll
      for (int off = 1; off < 16; off <<= 1)
#pragma unroll
        for (int r = 0; r < 4; ++r) cm[r] = fmaxf(cm[r], __shfl_xor(cm[r], off));
#pragma unroll
      for (int r = 0; r < 4; ++r) {
        float mn = fmaxf(m2[r], cm[r] * C);
        float alpha = exp2f(m2[r] - mn);
        m2[r] = mn;
        lsum[r] *= alpha;
        accO[0][r] *= alpha; accO[1][r] *= alpha;
        accO[2][r] *= alpha; accO[3][r] *= alpha;
      }
    }

    // P = exp2(s*C - m2); per-lane partial lsum; cheap-rounded bf16 store
#pragma unroll
    for (int kf = 0; kf < 4; ++kf) {
#pragma unroll
      for (int r = 0; r < 4; ++r) {
        float p = exp2f(s[kf][r] * C - m2[r]);
        lsum[r] += p;
        int row = rl + r;
        int boff = (row * 128 + (kf * 16 + cl) * 2) ^ ((row & 7) << 4);
        *(unsigned short*)(Pw + boff) =
            (unsigned short)((__float_as_uint(p) + 0x8000u) >> 16);
      }
    }

    // PV: O[16q][64d] += P @ V
    __builtin_amdgcn_s_setprio(1);
#pragma unroll
    for (int ks = 0; ks < 2; ++ks) {
      int pboff = (cl * 128 + ks * 64 + kg * 16) ^ ((cl & 7) << 4);
      bf16x8 ap = *(const bf16x8*)(Pw + pboff);
#pragma unroll
      for (int df = 0; df < 4; ++df) {
        int d = df * 16 + cl;
        int vboff = (d * 128 + ks * 64 + kg * 16) ^ ((d & 7) << 4);
        accO[df] = __builtin_amdgcn_mfma_f32_16x16x32_bf16(
            ap, *(const bf16x8*)((char*)Vs[cur] + vboff), accO[df], 0, 0, 0);
      }
    }
    __builtin_amdgcn_s_setprio(0);

    __syncthreads();  // DMA for next buf drained + all reads of cur done
  }

  // deferred lsum reduce across the 16-lane row group
#pragma unroll
  for (int off = 1; off < 16; off <<= 1)
#pragma unroll
    for (int r = 0; r < 4; ++r) lsum[r] += __shfl_xor(lsum[r], off);

  float inv[4];
#pragma unroll
  for (int r = 0; r < 4; ++r) inv[r] = 1.f / lsum[r];
#pragma unroll
  for (int df = 0; df < 4; ++df)
#pragma unroll
    for (int r = 0; r < 4; ++r) {
      int q = q0 + rl + r;
      int d = df * 16 + cl;
      valsb[(((size_t)b * 1024) + q) * 512 + h * 64 + d] = f2bf(accO[df][r] * inv[r]);
    }
}

// ---------------------------------------------------------------------------
// Fused residual + LayerNorm: h = LN(h + res_bf16) -> h (fp32) + hb (bf16).
// ---------------------------------------------------------------------------
__global__ __launch_bounds__(256) void ln_residual(
    float* __restrict__ h, const unsigned short* __restrict__ res,
    const float* __restrict__ g, const float* __restrict__ bb,
    unsigned short* __restrict__ hb) {
  int row = blockIdx.x * 4 + (threadIdx.x >> 6);
  int lane = threadIdx.x & 63;
  size_t base = (size_t)row * 512 + lane * 8;
  float4 v0 = *(const float4*)&h[base];
  float4 v1 = *(const float4*)&h[base + 4];
  u16x8 rv = *(const u16x8*)&res[base];
  float xv[8];
  xv[0] = v0.x + bf2f(rv[0]); xv[1] = v0.y + bf2f(rv[1]);
  xv[2] = v0.z + bf2f(rv[2]); xv[3] = v0.w + bf2f(rv[3]);
  xv[4] = v1.x + bf2f(rv[4]); xv[5] = v1.y + bf2f(rv[5]);
  xv[6] = v1.z + bf2f(rv[6]); xv[7] = v1.w + bf2f(rv[7]);
  float s = 0.f, sq = 0.f;
#pragma unroll
  for (int i = 0; i < 8; ++i) { s += xv[i]; sq += xv[i] * xv[i]; }
#pragma unroll
  for (int off = 32; off; off >>= 1) { s += __shfl_xor(s, off); sq += __shfl_xor(sq, off); }
  float mu = s * (1.f / 512.f);
  float var = sq * (1.f / 512.f) - mu * mu;
  float rstd = rsqrtf(var + EPS);
  float4 g0 = *(const float4*)&g[lane * 8];
  float4 g1 = *(const float4*)&g[lane * 8 + 4];
  float4 b0 = *(const float4*)&bb[lane * 8];
  float4 b1 = *(const float4*)&bb[lane * 8 + 4];
  float o[8];
  o[0] = (xv[0] - mu) * rstd * g0.x + b0.x;
  o[1] = (xv[1] - mu) * rstd * g0.y + b0.y;
  o[2] = (xv[2] - mu) * rstd * g0.z + b0.z;
  o[3] = (xv[3] - mu) * rstd * g0.w + b0.w;
  o[4] = (xv[4] - mu) * rstd * g1.x + b1.x;
  o[5] = (xv[5] - mu) * rstd * g1.y + b1.y;
  o[6] = (xv[6] - mu) * rstd * g1.z + b1.z;
  o[7] = (xv[7] - mu) * rstd * g1.w + b1.w;
  *(float4*)&h[base] = make_float4(o[0], o[1], o[2], o[3]);
  *(float4*)&h[base + 4] = make_float4(o[4], o[5], o[6], o[7]);
  u16x8 hv;
#pragma unroll
  for (int i = 0; i < 8; ++i) hv[i] = f2bf(o[i]);
  *(u16x8*)&hb[base] = hv;
}

// ---------------------------------------------------------------------------
__global__ __launch_bounds__(512) void pool_kernel(
    const float* __restrict__ h, float* __restrict__ partial) {
  int b = blockIdx.x >> 3, c = blockIdx.x & 7, d = threadIdx.x;
  float s = 0.f;
  for (int t = 0; t < 128; ++t)
    s += h[((size_t)b * 1024 + c * 128 + t) * 512 + d];
  partial[(size_t)blockIdx.x * 512 + d] = s;
}

__global__ __launch_bounds__(512) void head_kernel(
    const float* __restrict__ partial, const float* __restrict__ W1,
    const float* __restrict__ b1, const float* __restrict__ g,
    const float* __restrict__ bb, const float* __restrict__ W2,
    const float* __restrict__ b2, float* __restrict__ out) {
  int b = blockIdx.x, tid = threadIdx.x;
  int wid = tid >> 6, lane = tid & 63;
  __shared__ float ps[512];
  __shared__ float red_s[8];
  __shared__ float red_q[8];
  float pv = 0.f;
#pragma unroll
  for (int c = 0; c < 8; ++c) pv += partial[((size_t)(b * 8 + c)) * 512 + tid];
  ps[tid] = pv * (1.f / 1024.f);
  __syncthreads();
  float acc = b1[tid];
  for (int k = 0; k < 512; ++k) acc += ps[k] * W1[(size_t)k * 512 + tid];
  float s = acc, sq = acc * acc;
#pragma unroll
  for (int off = 32; off; off >>= 1) { s += __shfl_xor(s, off); sq += __shfl_xor(sq, off); }
  if (lane == 0) { red_s[wid] = s; red_q[wid] = sq; }
  __syncthreads();
  float S = 0.f, Q = 0.f;
#pragma unroll
  for (int i = 0; i < 8; ++i) { S += red_s[i]; Q += red_q[i]; }
  float mu = S * (1.f / 512.f);
  float var = Q * (1.f / 512.f) - mu * mu;
  float rstd = rsqrtf(var + EPS);
  float z = (acc - mu) * rstd * g[tid] + bb[tid];
  float r = fmaxf(z, 0.f);
  float v = r * W2[tid];
#pragma unroll
  for (int off = 32; off; off >>= 1) v += __shfl_xor(v, off);
  __syncthreads();
  if (lane == 0) red_s[wid] = v;
  __syncthreads();
  if (tid == 0) {
    float t = 0.f;
#pragma unroll
    for (int i = 0; i < 8; ++i) t += red_s[i];
    out[b] = t + b2[0];
  }
}

// ---------------------------------------------------------------------------
extern "C" void kernel_launch(void* const* d_in, const int* in_sizes, int n_in,
                              void* d_out, int out_size, void* d_ws, size_t ws_size,
                              hipStream_t stream) {
  const float* x    = (const float*)d_in[0];
  const int*   pos  = (const int*)d_in[1];
  const float* pe   = (const float*)d_in[2];
  const float* inW  = (const float*)d_in[3];
  const float* inb  = (const float*)d_in[4];
  const float* qkvW = (const float*)d_in[5];
  const float* qkvb = (const float*)d_in[6];
  const float* oW   = (const float*)d_in[7];
  const float* ob   = (const float*)d_in[8];
  const float* f1W  = (const float*)d_in[9];
  const float* f1b  = (const float*)d_in[10];
  const float* f2W  = (const float*)d_in[11];
  const float* f2b  = (const float*)d_in[12];
  const float* l1g  = (const float*)d_in[13];
  const float* l1b  = (const float*)d_in[14];
  const float* l2g  = (const float*)d_in[15];
  const float* l2b  = (const float*)d_in[16];
  const float* o1W  = (const float*)d_in[17];
  const float* o1b  = (const float*)d_in[18];
  const float* og   = (const float*)d_in[19];
  const float* obb  = (const float*)d_in[20];
  const float* o2W  = (const float*)d_in[21];
  const float* o2b  = (const float*)d_in[22];
  float* out = (float*)d_out;

  char* W = (char*)d_ws;
  float*          h     = (float*)(W + 0);                 // 16 MB
  unsigned short* hb    = (unsigned short*)(W + 16777216); // 8 MB
  unsigned short* qTb   = (unsigned short*)(W + 25165824); // 8 MB
  unsigned short* kTb   = (unsigned short*)(W + 33554432); // 8 MB
  unsigned short* vTb   = (unsigned short*)(W + 41943040); // 8 MB [bh][d][s]
  unsigned short* valsb = (unsigned short*)(W + 50331648); // 8 MB
  unsigned short* projb = (unsigned short*)(W + 25165824); // aliases qT
  unsigned short* ff1b  = (unsigned short*)(W + 41943040); // aliases vT+vals
  unsigned short* wt    = (unsigned short*)(W + 58720256); // 4 MB
  float*          part  = (float*)(W + 62914560);

  unsigned short* wt_qkv = wt;
  unsigned short* wt_o   = wt + 786432;
  unsigned short* wt_f1  = wt + 1048576;
  unsigned short* wt_f2  = wt + 1572864;

  inproj_kernel<<<8192, 512, 0, stream>>>(x, pos, pe, inW, inb, h, hb);

  for (int l = 0; l < 6; ++l) {
    wcast_kernel<<<512, 256, 0, stream>>>(
        qkvW + (size_t)l * 512 * 1536, oW + (size_t)l * 512 * 512,
        f1W + (size_t)l * 512 * 1024, f2W + (size_t)l * 1024 * 512,
        wt_qkv, wt_o, wt_f1, wt_f2);

    // qkv: 12 x-tiles x 64 y-tiles = 768 blocks (768%8==0)
    gemm_bf16<2, 128, 12><<<768, 256, 0, stream>>>(
        hb, wt_qkv, qkvb + l * 1536, nullptr, qTb, kTb, vTb, 8192, 1536, 512);

    attn_mfma<<<1024, 256, 0, stream>>>(qTb, kTb, vTb, valsb);

    // o-proj: 4 x-tiles x 128 y-tiles = 512 blocks
    gemm_bf16<3, 64, 4><<<512, 256, 0, stream>>>(
        valsb, wt_o, ob + l * 512, projb, nullptr, nullptr, nullptr, 8192, 512, 512);

    ln_residual<<<2048, 256, 0, stream>>>(h, projb, l1g + l * 512, l1b + l * 512, hb);

    // ff1: 8 x-tiles x 64 y-tiles = 512 blocks
    gemm_bf16<1, 128, 8><<<512, 256, 0, stream>>>(
        hb, wt_f1, f1b + l * 1024, ff1b, nullptr, nullptr, nullptr, 8192, 1024, 512);

    // ff2: 4 x-tiles x 128 y-tiles = 512 blocks
    gemm_bf16<3, 64, 4><<<512, 256, 0, stream>>>(
        ff1b, wt_f2, f2b + l * 512, projb, nullptr, nullptr, nullptr, 8192, 512, 1024);

    ln_residual<<<2048, 256, 0, stream>>>(h, projb, l2g + l * 512, l2b + l * 512, hb);
  }

  pool_kernel<<<64, 512, 0, stream>>>(h, part);
  head_kernel<<<8, 512, 0, stream>>>(part, o1W, o1b, og, obb, o2W, o2b, out);
}